// Round 13
// baseline (890.190 us; speedup 1.0000x reference)
//
#include <hip/hip_runtime.h>
#include <math.h>

#define NN 500
#define DD 64
#define NPAD 512             // adjT padded to [512][512]
#define COLS 65536           // 1024 * 64
#define BS_TOT 1024          // B*S
#define I_DIM 32000          // N*D
#define KS_GRU 40            // K-split for GRU pre-GEMM
#define KSL 800              // 32000/40

typedef __attribute__((ext_vector_type(8))) short bf16x8;
typedef __attribute__((ext_vector_type(4))) float f32x4;

__device__ __forceinline__ float gelu_f(float x) {
    return 0.5f * x * (1.0f + erff(x * 0.70710678118654752440f));
}

__device__ __forceinline__ unsigned short bf16_rn(float x) {
    unsigned int u = __float_as_uint(x);
    unsigned int r = u + 0x7FFFu + ((u >> 16) & 1u);
    return (unsigned short)(r >> 16);
}
__device__ __forceinline__ float bf16_tof(unsigned short h) {
    return __uint_as_float(((unsigned int)h) << 16);
}
// packed split-bf16: u = hi | (lo<<16); value = tof(hi)+tof(lo)
__device__ __forceinline__ unsigned int pack_hl(float x) {
    unsigned short h = bf16_rn(x);
    unsigned short l = bf16_rn(x - bf16_tof(h));
    return (unsigned int)h | ((unsigned int)l << 16);
}
__device__ __forceinline__ float unpack_val(unsigned int u) {
    return __uint_as_float(u << 16) + __uint_as_float(u & 0xFFFF0000u);
}
__device__ __forceinline__ void split4(float4 v, short4& h4, short4& l4) {
    h4.x = (short)bf16_rn(v.x); l4.x = (short)bf16_rn(v.x - bf16_tof((unsigned short)h4.x));
    h4.y = (short)bf16_rn(v.y); l4.y = (short)bf16_rn(v.y - bf16_tof((unsigned short)h4.y));
    h4.z = (short)bf16_rn(v.z); l4.z = (short)bf16_rn(v.z - bf16_tof((unsigned short)h4.z));
    h4.w = (short)bf16_rn(v.w); l4.w = (short)bf16_rn(v.w - bf16_tof((unsigned short)h4.w));
}

// LDS XOR swizzle (16B granularity within 64B k-extent)
__device__ __forceinline__ int swz_k(int row, int kbyte) {
    return kbyte ^ (((row >> 3) & 3) << 4);
}

// ---------------------------------------------------------------- adjacency
__global__ __launch_bounds__(512)
void adj_kernel(const float* __restrict__ fe, const float* __restrict__ te,
                short* __restrict__ adjTh, short* __restrict__ adjTl)
{
    __shared__ float fr[32];
    __shared__ float red[8];
    __shared__ float red2[8];
    const int n = blockIdx.x;
    const int tid = threadIdx.x;
    if (tid < 32) fr[tid] = fe[n * 32 + tid];
    __syncthreads();
    const int m = tid;
    float s = -1e30f;
    if (m < NN) {
        float acc = 0.f;
        #pragma unroll
        for (int f = 0; f < 32; ++f) acc += fr[f] * te[m * 32 + f];
        s = acc * 2.0f;   // 1/TEMP
    }
    float v = s;
    #pragma unroll
    for (int off = 32; off; off >>= 1) v = fmaxf(v, __shfl_xor(v, off));
    if ((tid & 63) == 0) red[tid >> 6] = v;
    __syncthreads();
    float bmax = red[0];
    #pragma unroll
    for (int i = 1; i < 8; ++i) bmax = fmaxf(bmax, red[i]);
    float e = (m < NN) ? expf(s - bmax) : 0.f;
    float v2 = e;
    #pragma unroll
    for (int off = 32; off; off >>= 1) v2 += __shfl_xor(v2, off);
    if ((tid & 63) == 0) red2[tid >> 6] = v2;
    __syncthreads();
    float bsum = 0.f;
    #pragma unroll
    for (int i = 0; i < 8; ++i) bsum += red2[i];
    if (m < NN) {
        float p = e / bsum;
        unsigned short h = bf16_rn(p);
        adjTh[(size_t)m * NPAD + n] = (short)h;
        adjTl[(size_t)m * NPAD + n] = (short)bf16_rn(p - bf16_tof(h));
    }
}

// ---------------------------------------------------------------- generic split-convert
__global__ __launch_bounds__(256)
void wsplit_kernel(const float* __restrict__ W, short* __restrict__ H,
                   short* __restrict__ L, int n4)
{
    int i = blockIdx.x * 256 + threadIdx.x;
    if (i < n4) {
        float4 v = *(const float4*)&W[i * 4];
        short4 h4, l4;
        split4(v, h4, l4);
        *(short4*)&H[i * 4] = h4;
        *(short4*)&L[i * 4] = l4;
    }
}

// ---------------------------------------------------------------- input proj (streaming MFMA, no LDS)
__global__ __launch_bounds__(256)
void proj_mfma_kernel(const float* __restrict__ xin,
                      const short* __restrict__ Wh, const short* __restrict__ Wl,
                      const float* __restrict__ ipb, unsigned int* __restrict__ Xhl)
{
    const int tid  = threadIdx.x;
    const int lane = tid & 63;
    const int wave = tid >> 6;
    const int q = lane >> 4, r16 = lane & 15;
    const size_t row0 = (size_t)blockIdx.x * 128 + wave * 32;

    float bB[4];
    #pragma unroll
    for (int ci = 0; ci < 4; ++ci) bB[ci] = ipb[ci * 16 + r16];

    bf16x8 wh[4], wl[4];
    #pragma unroll
    for (int ci = 0; ci < 4; ++ci) {
        int off = (ci * 16 + r16) * 32 + q * 8;
        wh[ci] = *(const bf16x8*)&Wh[off];
        wl[ci] = *(const bf16x8*)&Wl[off];
    }

    f32x4 acc[2][4];
    #pragma unroll
    for (int i = 0; i < 2; ++i)
        #pragma unroll
        for (int j = 0; j < 4; ++j) acc[i][j] = (f32x4){0.f, 0.f, 0.f, 0.f};

    #pragma unroll
    for (int mi = 0; mi < 2; ++mi) {
        const size_t row = row0 + mi * 16 + r16;
        const int n = (int)(row >> 10), bs = (int)(row & 1023);
        const float* src = &xin[((size_t)bs * NN + n) * 32 + q * 8];
        float4 v0 = *(const float4*)src;
        float4 v1 = *(const float4*)(src + 4);
        short4 h0, l0, h1, l1;
        split4(v0, h0, l0);
        split4(v1, h1, l1);
        bf16x8 ah, al;
        ah[0] = h0.x; ah[1] = h0.y; ah[2] = h0.z; ah[3] = h0.w;
        ah[4] = h1.x; ah[5] = h1.y; ah[6] = h1.z; ah[7] = h1.w;
        al[0] = l0.x; al[1] = l0.y; al[2] = l0.z; al[3] = l0.w;
        al[4] = l1.x; al[5] = l1.y; al[6] = l1.z; al[7] = l1.w;
        #pragma unroll
        for (int ci = 0; ci < 4; ++ci) {
            acc[mi][ci] = __builtin_amdgcn_mfma_f32_16x16x32_bf16(ah, wh[ci], acc[mi][ci], 0, 0, 0);
            acc[mi][ci] = __builtin_amdgcn_mfma_f32_16x16x32_bf16(ah, wl[ci], acc[mi][ci], 0, 0, 0);
            acc[mi][ci] = __builtin_amdgcn_mfma_f32_16x16x32_bf16(al, wh[ci], acc[mi][ci], 0, 0, 0);
        }
    }

    #pragma unroll
    for (int mi = 0; mi < 2; ++mi) {
        #pragma unroll
        for (int rg = 0; rg < 4; ++rg) {
            size_t grow = row0 + mi * 16 + q * 4 + rg;
            #pragma unroll
            for (int ci = 0; ci < 4; ++ci) {
                float y = gelu_f(acc[mi][ci][rg] + bB[ci]);
                Xhl[grow * 64 + ci * 16 + r16] = pack_hl(y);
            }
        }
    }
}

// ---------------------------------------------------------------- agg GEMM (split-bf16 MFMA, dbuf, A direct-from-L2)
// C[m][c] = sum_n adjT[m][n]*X[n][c] + X[m][c]; packed in/out.
// A (adjT, 1 MB, L2-hot) fragments loaded straight from global; only B in LDS.
__global__ __launch_bounds__(256)
void agg_mfma_kernel(const unsigned int* __restrict__ Xhl,
                     const short* __restrict__ adjTh, const short* __restrict__ adjTl,
                     unsigned int* __restrict__ Yhl)
{
    __shared__ __align__(16) short Bh[2][128 * 40];
    __shared__ __align__(16) short Bl[2][128 * 40];

    const int tid  = threadIdx.x;
    const int lane = tid & 63;
    const int wave = tid >> 6;
    const int wm = (wave >> 1) * 64;
    const int wc = (wave & 1) * 64;
    const int q = lane >> 4, r16 = lane & 15;
    const int m0 = blockIdx.x * 128;   // m fastest: 4 sibling blocks share B strip
    const int c0 = blockIdx.y * 128;

    const int sb_c = tid & 127, sb_kh = tid >> 7;
    const size_t cb = (size_t)(c0 + sb_c);

    f32x4 acc[4][4];
    #pragma unroll
    for (int i = 0; i < 4; ++i)
        #pragma unroll
        for (int j = 0; j < 4; ++j) acc[i][j] = (f32x4){0.f, 0.f, 0.f, 0.f};

    // ---- prologue: stage B chunk 0 into buffer 0
    {
        unsigned int u[16];
        #pragma unroll
        for (int j = 0; j < 16; ++j) {
            int kk = sb_kh * 16 + j;
            u[j] = (kk < NN) ? Xhl[(size_t)kk * COLS + cb] : 0u;
        }
        bf16x8 bh0, bh1, bl0, bl1;
        #pragma unroll
        for (int j = 0; j < 8; ++j) {
            bh0[j] = (short)(u[j] & 0xFFFFu);     bl0[j] = (short)(u[j] >> 16);
            bh1[j] = (short)(u[8 + j] & 0xFFFFu); bl1[j] = (short)(u[8 + j] >> 16);
        }
        char* rbH = (char*)Bh[0] + sb_c * 80;
        char* rbL = (char*)Bl[0] + sb_c * 80;
        int kb0 = swz_k(sb_c, sb_kh * 32);
        int kb1 = swz_k(sb_c, sb_kh * 32 + 16);
        *(bf16x8*)(rbH + kb0) = bh0; *(bf16x8*)(rbH + kb1) = bh1;
        *(bf16x8*)(rbL + kb0) = bl0; *(bf16x8*)(rbL + kb1) = bl1;
    }
    __syncthreads();

    for (int kc = 0; kc < 16; ++kc) {
        const int cur = kc & 1;
        const int k0 = kc * 32;
        // ---- (1) issue next-chunk B global loads into registers
        unsigned int nu[16];
        if (kc < 15) {
            const int k0n = k0 + 32;
            #pragma unroll
            for (int j = 0; j < 16; ++j) {
                int kk = k0n + sb_kh * 16 + j;
                nu[j] = (kk < NN) ? Xhl[(size_t)kk * COLS + cb] : 0u;
            }
        }
        // ---- (2) A fragments direct from global (adjT zero-padded; rows/k >= 500 are 0)
        bf16x8 ah[4], al[4];
        #pragma unroll
        for (int mi = 0; mi < 4; ++mi) {
            const size_t base = (size_t)(m0 + wm + mi * 16 + r16) * NPAD + k0 + q * 8;
            ah[mi] = *(const bf16x8*)&adjTh[base];
            al[mi] = *(const bf16x8*)&adjTl[base];
        }
        // ---- (3) B frags from LDS + MFMA
        #pragma unroll
        for (int ci = 0; ci < 4; ++ci) {
            int row = wc + ci * 16 + r16;
            int kb = swz_k(row, q * 16);
            bf16x8 bh = *(const bf16x8*)((const char*)Bh[cur] + row * 80 + kb);
            bf16x8 bl = *(const bf16x8*)((const char*)Bl[cur] + row * 80 + kb);
            #pragma unroll
            for (int mi = 0; mi < 4; ++mi) {
                acc[mi][ci] = __builtin_amdgcn_mfma_f32_16x16x32_bf16(ah[mi], bh, acc[mi][ci], 0, 0, 0);
                acc[mi][ci] = __builtin_amdgcn_mfma_f32_16x16x32_bf16(ah[mi], bl, acc[mi][ci], 0, 0, 0);
                acc[mi][ci] = __builtin_amdgcn_mfma_f32_16x16x32_bf16(al[mi], bh, acc[mi][ci], 0, 0, 0);
            }
        }
        // ---- (4) write next B chunk into buf cur^1
        if (kc < 15) {
            const int nb = cur ^ 1;
            bf16x8 bh0, bh1, bl0, bl1;
            #pragma unroll
            for (int j = 0; j < 8; ++j) {
                bh0[j] = (short)(nu[j] & 0xFFFFu);     bl0[j] = (short)(nu[j] >> 16);
                bh1[j] = (short)(nu[8 + j] & 0xFFFFu); bl1[j] = (short)(nu[8 + j] >> 16);
            }
            char* rbH = (char*)Bh[nb] + sb_c * 80;
            char* rbL = (char*)Bl[nb] + sb_c * 80;
            int kb0 = swz_k(sb_c, sb_kh * 32);
            int kb1 = swz_k(sb_c, sb_kh * 32 + 16);
            *(bf16x8*)(rbH + kb0) = bh0; *(bf16x8*)(rbH + kb1) = bh1;
            *(bf16x8*)(rbL + kb0) = bl0; *(bf16x8*)(rbL + kb1) = bl1;
        }
        // ---- (5) single barrier per chunk
        __syncthreads();
    }

    // ---- epilogue: residual + store packed
    #pragma unroll
    for (int mi = 0; mi < 4; ++mi) {
        #pragma unroll
        for (int r = 0; r < 4; ++r) {
            int m = m0 + wm + mi * 16 + q * 4 + r;
            if (m < NN) {
                #pragma unroll
                for (int ci = 0; ci < 4; ++ci) {
                    size_t idx = (size_t)m * COLS + c0 + wc + ci * 16 + r16;
                    float y = acc[mi][ci][r] + unpack_val(Xhl[idx]);
                    Yhl[idx] = pack_hl(y);
                }
            }
        }
    }
}

// ---------------------------------------------------------------- h + LN, streaming MFMA (no LDS, no barriers, in-place)
__global__ __launch_bounds__(256)
void hln_stream_kernel(unsigned int* __restrict__ Xio,
                       const short* __restrict__ Wh, const short* __restrict__ Wl,
                       const float* __restrict__ glb, const float* __restrict__ glg,
                       const float* __restrict__ glbe)
{
    const int tid  = threadIdx.x;
    const int lane = tid & 63;
    const int wave = tid >> 6;
    const int q = lane >> 4, r16 = lane & 15;
    const size_t row0 = (size_t)blockIdx.x * 128 + wave * 32;

    float bB2[4], bG2[4], bE2[4];
    #pragma unroll
    for (int ci = 0; ci < 4; ++ci) {
        int e = ci * 16 + r16;
        bB2[ci] = glb[e]; bG2[ci] = glg[e]; bE2[ci] = glbe[e];
    }

    f32x4 acc[2][4];
    #pragma unroll
    for (int i = 0; i < 2; ++i)
        #pragma unroll
        for (int j = 0; j < 4; ++j) acc[i][j] = (f32x4){0.f, 0.f, 0.f, 0.f};

    #pragma unroll
    for (int kh = 0; kh < 2; ++kh) {
        bf16x8 wh[4], wl[4];
        #pragma unroll
        for (int ci = 0; ci < 4; ++ci) {
            int off = (ci * 16 + r16) * 64 + kh * 32 + q * 8;
            wh[ci] = *(const bf16x8*)&Wh[off];
            wl[ci] = *(const bf16x8*)&Wl[off];
        }
        #pragma unroll
        for (int mi = 0; mi < 2; ++mi) {
            const size_t row = row0 + mi * 16 + r16;
            const unsigned int* src = &Xio[row * 64 + kh * 32 + q * 8];
            uint4 u0 = *(const uint4*)src;
            uint4 u1 = *(const uint4*)(src + 4);
            bf16x8 ah, al;
            ah[0] = (short)(u0.x & 0xFFFFu); al[0] = (short)(u0.x >> 16);
            ah[1] = (short)(u0.y & 0xFFFFu); al[1] = (short)(u0.y >> 16);
            ah[2] = (short)(u0.z & 0xFFFFu); al[2] = (short)(u0.z >> 16);
            ah[3] = (short)(u0.w & 0xFFFFu); al[3] = (short)(u0.w >> 16);
            ah[4] = (short)(u1.x & 0xFFFFu); al[4] = (short)(u1.x >> 16);
            ah[5] = (short)(u1.y & 0xFFFFu); al[5] = (short)(u1.y >> 16);
            ah[6] = (short)(u1.z & 0xFFFFu); al[6] = (short)(u1.z >> 16);
            ah[7] = (short)(u1.w & 0xFFFFu); al[7] = (short)(u1.w >> 16);
            #pragma unroll
            for (int ci = 0; ci < 4; ++ci) {
                acc[mi][ci] = __builtin_amdgcn_mfma_f32_16x16x32_bf16(ah, wh[ci], acc[mi][ci], 0, 0, 0);
                acc[mi][ci] = __builtin_amdgcn_mfma_f32_16x16x32_bf16(ah, wl[ci], acc[mi][ci], 0, 0, 0);
                acc[mi][ci] = __builtin_amdgcn_mfma_f32_16x16x32_bf16(al, wh[ci], acc[mi][ci], 0, 0, 0);
            }
        }
    }

    #pragma unroll
    for (int mi = 0; mi < 2; ++mi) {
        #pragma unroll
        for (int rg = 0; rg < 4; ++rg) {
            float h[4];
            float s1 = 0.f;
            #pragma unroll
            for (int ci = 0; ci < 4; ++ci) {
                h[ci] = gelu_f(acc[mi][ci][rg] + bB2[ci]);
                s1 += h[ci];
            }
            #pragma unroll
            for (int off = 1; off < 16; off <<= 1) s1 += __shfl_xor(s1, off);
            float mu = s1 * (1.f / 64.f);
            float s2 = 0.f;
            #pragma unroll
            for (int ci = 0; ci < 4; ++ci) { float dc = h[ci] - mu; s2 += dc * dc; }
            #pragma unroll
            for (int off = 1; off < 16; off <<= 1) s2 += __shfl_xor(s2, off);
            float rs = 1.f / sqrtf(s2 * (1.f / 64.f) + 1e-5f);
            size_t grow = row0 + mi * 16 + q * 4 + rg;
            #pragma unroll
            for (int ci = 0; ci < 4; ++ci) {
                float y = (h[ci] - mu) * rs * bG2[ci] + bE2[ci];
                Xio[grow * 64 + ci * 16 + r16] = pack_hl(y);
            }
        }
    }
}

// ---------------------------------------------------------------- Wih split-convert
__global__ __launch_bounds__(256)
void wconv_kernel(const float* __restrict__ W0, const float* __restrict__ W1,
                  const float* __restrict__ W2,
                  short* __restrict__ h0, short* __restrict__ l0,
                  short* __restrict__ h1, short* __restrict__ l1,
                  short* __restrict__ h2, short* __restrict__ l2)
{
    const int gi = blockIdx.y;
    const float* W = (gi == 0) ? W0 : (gi == 1) ? W1 : W2;
    short* H = (gi == 0) ? h0 : (gi == 1) ? h1 : h2;
    short* L = (gi == 0) ? l0 : (gi == 1) ? l1 : l2;
    const size_t i = ((size_t)blockIdx.x * 256 + threadIdx.x) * 4;
    float4 v = *(const float4*)&W[i];
    short4 h4, l4;
    split4(v, h4, l4);
    *(short4*)&H[i] = h4;
    *(short4*)&L[i] = l4;
}

// ---------------------------------------------------------------- GRU pre-GEMM (MFMA)
// blocks: [0,40)=s ks; [40,120)=m; [120,760)=l.  ks-major within each GRU so
// blocks sharing a W k-slice are 40 apart (40%8==0 -> same XCD -> L2-hot W).
__global__ __launch_bounds__(256)
void gru_pre_mfma_kernel(const unsigned int* __restrict__ Xhl,
                         const short* __restrict__ Wh0, const short* __restrict__ Wl0,
                         const short* __restrict__ Wh1, const short* __restrict__ Wl1,
                         const short* __restrict__ Wh2, const short* __restrict__ Wl2,
                         float* __restrict__ p0, float* __restrict__ p1,
                         float* __restrict__ p2)
{
    __shared__ __align__(16) short Ah[64 * 40];
    __shared__ __align__(16) short Al[64 * 40];
    __shared__ __align__(16) short Bh[192 * 40];
    __shared__ __align__(16) short Bl[192 * 40];

    const int bid = blockIdx.x;
    int gi, mtid, ks;
    if (bid < 40)       { gi = 0; mtid = 0;             ks = bid; }
    else if (bid < 120) { int r = bid - 40;  gi = 1; ks = r % 40; mtid = r / 40; }
    else                { int r = bid - 120; gi = 2; ks = r % 40; mtid = r / 40; }
    const short* Wh = (gi == 0) ? Wh0 : (gi == 1) ? Wh1 : Wh2;
    const short* Wl = (gi == 0) ? Wl0 : (gi == 1) ? Wl1 : Wl2;
    float* partial  = (gi == 0) ? p0 : (gi == 1) ? p1 : p2;
    const int Trows = (gi == 0) ? 10 : (gi == 1) ? 20 : 256;
    const int toff  = (gi == 0) ? 246 : (gi == 1) ? 236 : 0;
    const int M     = (gi == 0) ? 40 : (gi == 1) ? 80 : 1024;
    const int R0 = mtid * 64;

    const int tid  = threadIdx.x;
    const int lane = tid & 63;
    const int wave = tid >> 6;
    const int wr = (wave & 1) * 32;
    const int wg = (wave >> 1) * 96;
    const int q = lane >> 4, r16 = lane & 15;

    const int sa_r = tid >> 2, sa_kq = tid & 3;
    const bool vldA = (R0 + sa_r < M);
    int btA = 0;
    if (vldA) { int R = R0 + sa_r; int b = R / Trows, t = R - b * Trows; btA = b * 256 + toff + t; }

    f32x4 acc[2][6];
    #pragma unroll
    for (int i = 0; i < 2; ++i)
        #pragma unroll
        for (int j = 0; j < 6; ++j) acc[i][j] = (f32x4){0.f, 0.f, 0.f, 0.f};

    for (int c = 0; c < KSL / 32; ++c) {
        const int k0 = ks * KSL + c * 32;
        {
            const int kk = k0 + sa_kq * 8;
            const int nn = kk >> 6, d0 = kk & 63;
            uint4 u0 = make_uint4(0u, 0u, 0u, 0u), u1 = u0;
            if (vldA) {
                const unsigned int* src = &Xhl[((size_t)nn * BS_TOT + btA) * 64 + d0];
                u0 = *(const uint4*)src;
                u1 = *(const uint4*)(src + 4);
            }
            short4 h0 = make_short4((short)(u0.x & 0xFFFF), (short)(u0.y & 0xFFFF),
                                    (short)(u0.z & 0xFFFF), (short)(u0.w & 0xFFFF));
            short4 l0 = make_short4((short)(u0.x >> 16), (short)(u0.y >> 16),
                                    (short)(u0.z >> 16), (short)(u0.w >> 16));
            short4 h1 = make_short4((short)(u1.x & 0xFFFF), (short)(u1.y & 0xFFFF),
                                    (short)(u1.z & 0xFFFF), (short)(u1.w & 0xFFFF));
            short4 l1 = make_short4((short)(u1.x >> 16), (short)(u1.y >> 16),
                                    (short)(u1.z >> 16), (short)(u1.w >> 16));
            int kb = swz_k(sa_r, sa_kq * 16);
            char* rowH = (char*)Ah + sa_r * 80;
            char* rowL = (char*)Al + sa_r * 80;
            *(short4*)(rowH + kb) = h0; *(short4*)(rowH + kb + 8) = h1;
            *(short4*)(rowL + kb) = l0; *(short4*)(rowL + kb + 8) = l1;
        }
        #pragma unroll
        for (int l = 0; l < 3; ++l) {
            int idx = tid + l * 256;
            int g = idx >> 2, kq = idx & 3;
            const size_t src = (size_t)g * I_DIM + k0 + kq * 8;
            bf16x8 hv = *(const bf16x8*)&Wh[src];
            bf16x8 lv = *(const bf16x8*)&Wl[src];
            int kb = swz_k(g, kq * 16);
            *(bf16x8*)((char*)Bh + g * 80 + kb) = hv;
            *(bf16x8*)((char*)Bl + g * 80 + kb) = lv;
        }
        __syncthreads();
        bf16x8 ah[2], al[2];
        #pragma unroll
        for (int mi = 0; mi < 2; ++mi) {
            int row = wr + mi * 16 + r16;
            int kb = swz_k(row, q * 16);
            ah[mi] = *(const bf16x8*)((const char*)Ah + row * 80 + kb);
            al[mi] = *(const bf16x8*)((const char*)Al + row * 80 + kb);
        }
        #pragma unroll
        for (int ci = 0; ci < 6; ++ci) {
            int grow = wg + ci * 16 + r16;
            int kb = swz_k(grow, q * 16);
            bf16x8 bh = *(const bf16x8*)((const char*)Bh + grow * 80 + kb);
            bf16x8 bl = *(const bf16x8*)((const char*)Bl + grow * 80 + kb);
            #pragma unroll
            for (int mi = 0; mi < 2; ++mi) {
                acc[mi][ci] = __builtin_amdgcn_mfma_f32_16x16x32_bf16(ah[mi], bh, acc[mi][ci], 0, 0, 0);
                acc[mi][ci] = __builtin_amdgcn_mfma_f32_16x16x32_bf16(ah[mi], bl, acc[mi][ci], 0, 0, 0);
                acc[mi][ci] = __builtin_amdgcn_mfma_f32_16x16x32_bf16(al[mi], bh, acc[mi][ci], 0, 0, 0);
            }
        }
        __syncthreads();
    }
    #pragma unroll
    for (int mi = 0; mi < 2; ++mi) {
        #pragma unroll
        for (int r = 0; r < 4; ++r) {
            int R = R0 + wr + mi * 16 + q * 4 + r;
            if (R < M) {
                #pragma unroll
                for (int ci = 0; ci < 6; ++ci)
                    partial[((size_t)ks * M + R) * 192 + wg + ci * 16 + r16] = acc[mi][ci][r];
            }
        }
    }
}

// ---------------------------------------------------------------- reduce (all 3 fused)
__global__ __launch_bounds__(192)
void gru_reduce_fused_kernel(const float* __restrict__ p0, const float* __restrict__ p1,
                             const float* __restrict__ p2,
                             const float* __restrict__ bih0, const float* __restrict__ bih1,
                             const float* __restrict__ bih2,
                             float* __restrict__ xp0, float* __restrict__ xp1,
                             float* __restrict__ xp2)
{
    int r = blockIdx.x;
    const float* partial; const float* bih; float* xp; int M;
    if (r < 40)       { partial = p0; bih = bih0; xp = xp0; M = 40; }
    else if (r < 120) { r -= 40;  partial = p1; bih = bih1; xp = xp1; M = 80; }
    else              { r -= 120; partial = p2; bih = bih2; xp = xp2; M = 1024; }
    const int g = threadIdx.x;
    float acc = bih[g];
    for (int ks = 0; ks < KS_GRU; ++ks)
        acc += partial[((size_t)ks * M + r) * 192 + g];
    xp[(size_t)r * 192 + g] = acc;
}

// ---------------------------------------------------------------- GRU scan
__global__ __launch_bounds__(192)
void gru_scan_kernel(const float* __restrict__ xp_s, const float* __restrict__ xp_m,
                     const float* __restrict__ xp_l,
                     const float* __restrict__ Whh_s, const float* __restrict__ Whh_m,
                     const float* __restrict__ Whh_l,
                     const float* __restrict__ bhh_s, const float* __restrict__ bhh_m,
                     const float* __restrict__ bhh_l,
                     float* __restrict__ hcat)
{
    __shared__ float h[64];
    __shared__ float gh[192];
    const int blk = blockIdx.x;
    const int g3 = blk >> 2, b = blk & 3;
    const float* xp  = (g3 == 0) ? xp_s : (g3 == 1) ? xp_m : xp_l;
    const float* Whh = (g3 == 0) ? Whh_s : (g3 == 1) ? Whh_m : Whh_l;
    const float* bhh = (g3 == 0) ? bhh_s : (g3 == 1) ? bhh_m : bhh_l;
    const int T = (g3 == 0) ? 10 : (g3 == 1) ? 20 : 256;
    const int g = threadIdx.x;

    float w[64];
    #pragma unroll
    for (int k4 = 0; k4 < 16; ++k4) {
        float4 v = *(const float4*)&Whh[g * 64 + k4 * 4];
        w[k4 * 4 + 0] = v.x; w[k4 * 4 + 1] = v.y;
        w[k4 * 4 + 2] = v.z; w[k4 * 4 + 3] = v.w;
    }
    const float bh = bhh[g];
    if (g < 64) h[g] = 0.f;

    const float* xpb = xp + (size_t)b * T * 192;
    float xr_c = 0.f, xz_c = 0.f, xn_c = 0.f;
    if (g < 64) { xr_c = xpb[g]; xz_c = xpb[64 + g]; xn_c = xpb[128 + g]; }
    __syncthreads();

    for (int t = 0; t < T; ++t) {
        float xr_n = 0.f, xz_n = 0.f, xn_n = 0.f;
        if (t + 1 < T && g < 64) {
            const float* xq = xpb + (size_t)(t + 1) * 192;
            xr_n = xq[g]; xz_n = xq[64 + g]; xn_n = xq[128 + g];
        }
        float a0 = 0.f, a1 = 0.f, a2 = 0.f, a3 = 0.f;
        #pragma unroll
        for (int k4 = 0; k4 < 16; ++k4) {
            float4 hv = ((const float4*)h)[k4];
            a0 += hv.x * w[k4 * 4 + 0];
            a1 += hv.y * w[k4 * 4 + 1];
            a2 += hv.z * w[k4 * 4 + 2];
            a3 += hv.w * w[k4 * 4 + 3];
        }
        gh[g] = bh + ((a0 + a1) + (a2 + a3));
        __syncthreads();
        if (g < 64) {
            float hr = gh[g], hz = gh[64 + g], hn = gh[128 + g];
            float r = 1.f / (1.f + __expf(-(xr_c + hr)));
            float z = 1.f / (1.f + __expf(-(xz_c + hz)));
            float pre = xn_c + r * hn;
            float e2 = __expf(2.f * pre);
            float nv = 1.f - 2.f / (e2 + 1.f);   // tanh
            h[g] = (1.f - z) * nv + z * h[g];
        }
        __syncthreads();
        xr_c = xr_n; xz_c = xz_n; xn_c = xn_n;
    }
    if (g < 64) hcat[b * 192 + g3 * 64 + g] = h[g];
}

// ---------------------------------------------------------------- head
__global__ __launch_bounds__(512)
void head_kernel(const float* __restrict__ hcat,
                 const float* __restrict__ W1, const float* __restrict__ b1,
                 const float* __restrict__ W2, const float* __restrict__ b2,
                 float* __restrict__ out)
{
    __shared__ float hc[4][192];
    __shared__ float h1[4][64];
    const int tid = threadIdx.x;
    for (int i = tid; i < 768; i += 512) hc[i / 192][i % 192] = hcat[i];
    __syncthreads();
    if (tid < 256) {
        int b = tid >> 6, e = tid & 63;
        float acc = b1[e];
        #pragma unroll
        for (int k = 0; k < 192; ++k) acc += hc[b][k] * W1[e * 192 + k];
        h1[b][e] = gelu_f(acc);
    }
    __syncthreads();
    for (int o = tid; o < 2000; o += 512) {
        int b = o / 500, n = o % 500;
        float acc = b2[n];
        #pragma unroll
        for (int k = 0; k < 64; ++k) acc += h1[b][k] * W2[n * 64 + k];
        out[o] = acc;
    }
}

// ================================================================ launch
extern "C" void kernel_launch(void* const* d_in, const int* in_sizes, int n_in,
                              void* d_out, int out_size, void* d_ws, size_t ws_size,
                              hipStream_t stream)
{
    (void)in_sizes; (void)n_in; (void)out_size; (void)ws_size;
    const float* x    = (const float*)d_in[0];
    const float* ipW  = (const float*)d_in[1];
    const float* ipb  = (const float*)d_in[2];
    const float* fe   = (const float*)d_in[3];
    const float* te   = (const float*)d_in[4];
    const float* glW  = (const float*)d_in[5];
    const float* glb  = (const float*)d_in[6];
    const float* glg  = (const float*)d_in[7];
    const float* glbe = (const float*)d_in[8];
    const float* Wih[3] = {(const float*)d_in[9],  (const float*)d_in[13], (const float*)d_in[17]};
    const float* Whh[3] = {(const float*)d_in[10], (const float*)d_in[14], (const float*)d_in[18]};
    const float* bih[3] = {(const float*)d_in[11], (const float*)d_in[15], (const float*)d_in[19]};
    const float* bhh[3] = {(const float*)d_in[12], (const float*)d_in[16], (const float*)d_in[20]};
    const float* W1 = (const float*)d_in[21];
    const float* b1 = (const float*)d_in[22];
    const float* W2 = (const float*)d_in[23];
    const float* b2 = (const float*)d_in[24];
    float* out = (float*)d_out;

    unsigned int* Xhl = (unsigned int*)d_ws;          // 32,768,000 uints (131 MB)
    unsigned int* Yhl = Xhl + 32768000;               // 32,768,000 uints (131 MB)
    short* adjTh = (short*)(Yhl + 32768000);          // 512*512 shorts
    short* adjTl = adjTh + NPAD * NPAD;
    short* glWh  = adjTl + NPAD * NPAD;               // 8192 shorts (2 layers)
    short* glWl  = glWh + 8192;
    short* ipWh  = glWl + 8192;                       // 2048 shorts
    short* ipWl  = ipWh + 2048;
    // GRU-phase scratch overlays Yhl (dead after layer-2):
    short* wbase = (short*)Yhl;
    short* Wh0 = wbase;                               // 6,144,000 shorts each
    short* Wl0 = Wh0 + 6144000;
    short* Wh1 = Wl0 + 6144000;
    short* Wl1 = Wh1 + 6144000;
    short* Wh2 = Wl1 + 6144000;
    short* Wl2 = Wh2 + 6144000;
    float* pbase = (float*)Yhl + 18432000;
    float* part0 = pbase;                             // 40*40*192   = 307,200
    float* part1 = part0 + 307200;                    // 40*80*192   = 614,400
    float* part2 = part1 + 614400;                    // 40*1024*192 = 7,864,320
    float* xp0   = part2 + 7864320;                   // 7,680
    float* xp1   = xp0 + 7680;                        // 15,360
    float* xp2   = xp1 + 15360;                       // 196,608
    float* hcat  = xp2 + 196608;                      // 768

    hipMemsetAsync(adjTh, 0, (size_t)NPAD * NPAD * 2 * sizeof(short), stream);
    adj_kernel<<<NN, 512, 0, stream>>>(fe, te, adjTh, adjTl);
    wsplit_kernel<<<8, 256, 0, stream>>>(glW, glWh, glWl, 2048);
    wsplit_kernel<<<2, 256, 0, stream>>>(ipW, ipWh, ipWl, 512);
    proj_mfma_kernel<<<4000, 256, 0, stream>>>(x, ipWh, ipWl, ipb, Xhl);

    // layer 1: Xhl -> Yhl (agg+residual), then h+LN in-place on Yhl
    agg_mfma_kernel<<<dim3(4, 512), 256, 0, stream>>>(Xhl, adjTh, adjTl, Yhl);
    hln_stream_kernel<<<4000, 256, 0, stream>>>(Yhl, glWh, glWl, glb, glg, glbe);
    // layer 2: Yhl -> Xhl, then in-place on Xhl
    agg_mfma_kernel<<<dim3(4, 512), 256, 0, stream>>>(Yhl, adjTh, adjTl, Xhl);
    hln_stream_kernel<<<4000, 256, 0, stream>>>(Xhl, glWh + 4096, glWl + 4096,
                                                glb + 64, glg + 64, glbe + 64);

    wconv_kernel<<<dim3(6000, 3), 256, 0, stream>>>(Wih[0], Wih[1], Wih[2],
                                                    Wh0, Wl0, Wh1, Wl1, Wh2, Wl2);
    gru_pre_mfma_kernel<<<760, 256, 0, stream>>>(Xhl, Wh0, Wl0, Wh1, Wl1, Wh2, Wl2,
                                                 part0, part1, part2);
    gru_reduce_fused_kernel<<<1144, 192, 0, stream>>>(part0, part1, part2,
                                                      bih[0], bih[1], bih[2],
                                                      xp0, xp1, xp2);
    gru_scan_kernel<<<12, 192, 0, stream>>>(xp0, xp1, xp2,
                                            Whh[0], Whh[1], Whh[2],
                                            bhh[0], bhh[1], bhh[2], hcat);
    head_kernel<<<1, 512, 0, stream>>>(hcat, W1, b1, W2, b2, out);
}

// Round 14
// 865.882 us; speedup vs baseline: 1.0281x; 1.0281x over previous
//
#include <hip/hip_runtime.h>
#include <math.h>

#define NN 500
#define DD 64
#define NPAD 512             // adjT padded to [512][512]
#define COLS 65536           // 1024 * 64
#define BS_TOT 1024          // B*S
#define I_DIM 32000          // N*D
#define KS_GRU 40            // K-split for GRU pre-GEMM
#define KSL 800              // 32000/40

typedef __attribute__((ext_vector_type(8))) short bf16x8;
typedef __attribute__((ext_vector_type(4))) float f32x4;

__device__ __forceinline__ float gelu_f(float x) {
    return 0.5f * x * (1.0f + erff(x * 0.70710678118654752440f));
}

__device__ __forceinline__ unsigned short bf16_rn(float x) {
    unsigned int u = __float_as_uint(x);
    unsigned int r = u + 0x7FFFu + ((u >> 16) & 1u);
    return (unsigned short)(r >> 16);
}
__device__ __forceinline__ float bf16_tof(unsigned short h) {
    return __uint_as_float(((unsigned int)h) << 16);
}
// packed split-bf16: u = hi | (lo<<16); value = tof(hi)+tof(lo)
__device__ __forceinline__ unsigned int pack_hl(float x) {
    unsigned short h = bf16_rn(x);
    unsigned short l = bf16_rn(x - bf16_tof(h));
    return (unsigned int)h | ((unsigned int)l << 16);
}
__device__ __forceinline__ float unpack_val(unsigned int u) {
    return __uint_as_float(u << 16) + __uint_as_float(u & 0xFFFF0000u);
}
__device__ __forceinline__ void split4(float4 v, short4& h4, short4& l4) {
    h4.x = (short)bf16_rn(v.x); l4.x = (short)bf16_rn(v.x - bf16_tof((unsigned short)h4.x));
    h4.y = (short)bf16_rn(v.y); l4.y = (short)bf16_rn(v.y - bf16_tof((unsigned short)h4.y));
    h4.z = (short)bf16_rn(v.z); l4.z = (short)bf16_rn(v.z - bf16_tof((unsigned short)h4.z));
    h4.w = (short)bf16_rn(v.w); l4.w = (short)bf16_rn(v.w - bf16_tof((unsigned short)h4.w));
}

// LDS XOR swizzle (16B granularity within 64B k-extent)
__device__ __forceinline__ int swz_k(int row, int kbyte) {
    return kbyte ^ (((row >> 3) & 3) << 4);
}

// ---------------------------------------------------------------- adjacency
__global__ __launch_bounds__(512)
void adj_kernel(const float* __restrict__ fe, const float* __restrict__ te,
                short* __restrict__ adjTh, short* __restrict__ adjTl)
{
    __shared__ float fr[32];
    __shared__ float red[8];
    __shared__ float red2[8];
    const int n = blockIdx.x;
    const int tid = threadIdx.x;
    if (tid < 32) fr[tid] = fe[n * 32 + tid];
    __syncthreads();
    const int m = tid;
    float s = -1e30f;
    if (m < NN) {
        float acc = 0.f;
        #pragma unroll
        for (int f = 0; f < 32; ++f) acc += fr[f] * te[m * 32 + f];
        s = acc * 2.0f;   // 1/TEMP
    }
    float v = s;
    #pragma unroll
    for (int off = 32; off; off >>= 1) v = fmaxf(v, __shfl_xor(v, off));
    if ((tid & 63) == 0) red[tid >> 6] = v;
    __syncthreads();
    float bmax = red[0];
    #pragma unroll
    for (int i = 1; i < 8; ++i) bmax = fmaxf(bmax, red[i]);
    float e = (m < NN) ? expf(s - bmax) : 0.f;
    float v2 = e;
    #pragma unroll
    for (int off = 32; off; off >>= 1) v2 += __shfl_xor(v2, off);
    if ((tid & 63) == 0) red2[tid >> 6] = v2;
    __syncthreads();
    float bsum = 0.f;
    #pragma unroll
    for (int i = 0; i < 8; ++i) bsum += red2[i];
    if (m < NN) {
        float p = e / bsum;
        unsigned short h = bf16_rn(p);
        adjTh[(size_t)m * NPAD + n] = (short)h;
        adjTl[(size_t)m * NPAD + n] = (short)bf16_rn(p - bf16_tof(h));
    }
}

// ---------------------------------------------------------------- generic split-convert
__global__ __launch_bounds__(256)
void wsplit_kernel(const float* __restrict__ W, short* __restrict__ H,
                   short* __restrict__ L, int n4)
{
    int i = blockIdx.x * 256 + threadIdx.x;
    if (i < n4) {
        float4 v = *(const float4*)&W[i * 4];
        short4 h4, l4;
        split4(v, h4, l4);
        *(short4*)&H[i * 4] = h4;
        *(short4*)&L[i * 4] = l4;
    }
}

// ---------------------------------------------------------------- input proj (streaming MFMA, no LDS)
__global__ __launch_bounds__(256)
void proj_mfma_kernel(const float* __restrict__ xin,
                      const short* __restrict__ Wh, const short* __restrict__ Wl,
                      const float* __restrict__ ipb, unsigned int* __restrict__ Xhl)
{
    const int tid  = threadIdx.x;
    const int lane = tid & 63;
    const int wave = tid >> 6;
    const int q = lane >> 4, r16 = lane & 15;
    const size_t row0 = (size_t)blockIdx.x * 128 + wave * 32;

    float bB[4];
    #pragma unroll
    for (int ci = 0; ci < 4; ++ci) bB[ci] = ipb[ci * 16 + r16];

    bf16x8 wh[4], wl[4];
    #pragma unroll
    for (int ci = 0; ci < 4; ++ci) {
        int off = (ci * 16 + r16) * 32 + q * 8;
        wh[ci] = *(const bf16x8*)&Wh[off];
        wl[ci] = *(const bf16x8*)&Wl[off];
    }

    f32x4 acc[2][4];
    #pragma unroll
    for (int i = 0; i < 2; ++i)
        #pragma unroll
        for (int j = 0; j < 4; ++j) acc[i][j] = (f32x4){0.f, 0.f, 0.f, 0.f};

    #pragma unroll
    for (int mi = 0; mi < 2; ++mi) {
        const size_t row = row0 + mi * 16 + r16;
        const int n = (int)(row >> 10), bs = (int)(row & 1023);
        const float* src = &xin[((size_t)bs * NN + n) * 32 + q * 8];
        float4 v0 = *(const float4*)src;
        float4 v1 = *(const float4*)(src + 4);
        short4 h0, l0, h1, l1;
        split4(v0, h0, l0);
        split4(v1, h1, l1);
        bf16x8 ah, al;
        ah[0] = h0.x; ah[1] = h0.y; ah[2] = h0.z; ah[3] = h0.w;
        ah[4] = h1.x; ah[5] = h1.y; ah[6] = h1.z; ah[7] = h1.w;
        al[0] = l0.x; al[1] = l0.y; al[2] = l0.z; al[3] = l0.w;
        al[4] = l1.x; al[5] = l1.y; al[6] = l1.z; al[7] = l1.w;
        #pragma unroll
        for (int ci = 0; ci < 4; ++ci) {
            acc[mi][ci] = __builtin_amdgcn_mfma_f32_16x16x32_bf16(ah, wh[ci], acc[mi][ci], 0, 0, 0);
            acc[mi][ci] = __builtin_amdgcn_mfma_f32_16x16x32_bf16(ah, wl[ci], acc[mi][ci], 0, 0, 0);
            acc[mi][ci] = __builtin_amdgcn_mfma_f32_16x16x32_bf16(al, wh[ci], acc[mi][ci], 0, 0, 0);
        }
    }

    #pragma unroll
    for (int mi = 0; mi < 2; ++mi) {
        #pragma unroll
        for (int rg = 0; rg < 4; ++rg) {
            size_t grow = row0 + mi * 16 + q * 4 + rg;
            #pragma unroll
            for (int ci = 0; ci < 4; ++ci) {
                float y = gelu_f(acc[mi][ci][rg] + bB[ci]);
                Xhl[grow * 64 + ci * 16 + r16] = pack_hl(y);
            }
        }
    }
}

// ---------------------------------------------------------------- agg GEMM (split-bf16 MFMA)
// C[m][c] = sum_n adjT[m][n]*X[n][c] + X[m][c]; packed in/out.
// B: LDS double-buffer (single barrier/chunk).  A: REGISTER double-buffer,
// fragments prefetched one chunk ahead from L2-resident adjT (never in LDS).
__global__ __launch_bounds__(256)
void agg_mfma_kernel(const unsigned int* __restrict__ Xhl,
                     const short* __restrict__ adjTh, const short* __restrict__ adjTl,
                     unsigned int* __restrict__ Yhl)
{
    __shared__ __align__(16) short Bh[2][128 * 40];
    __shared__ __align__(16) short Bl[2][128 * 40];

    const int tid  = threadIdx.x;
    const int lane = tid & 63;
    const int wave = tid >> 6;
    const int wm = (wave >> 1) * 64;
    const int wc = (wave & 1) * 64;
    const int q = lane >> 4, r16 = lane & 15;
    const int c0 = blockIdx.x * 128;
    const int m0 = blockIdx.y * 128;

    const int sb_c = tid & 127, sb_kh = tid >> 7;
    const size_t cb = (size_t)(c0 + sb_c);

    // per-lane A-fragment row bases (adjT zero-padded to 512x512)
    size_t aRow[4];
    #pragma unroll
    for (int mi = 0; mi < 4; ++mi)
        aRow[mi] = (size_t)(m0 + wm + mi * 16 + r16) * NPAD + q * 8;

    f32x4 acc[4][4];
    #pragma unroll
    for (int i = 0; i < 4; ++i)
        #pragma unroll
        for (int j = 0; j < 4; ++j) acc[i][j] = (f32x4){0.f, 0.f, 0.f, 0.f};

    // ---- prologue: A frags chunk 0 into registers; B chunk 0 into LDS buf 0
    bf16x8 ahC[4], alC[4];
    #pragma unroll
    for (int mi = 0; mi < 4; ++mi) {
        ahC[mi] = *(const bf16x8*)&adjTh[aRow[mi]];
        alC[mi] = *(const bf16x8*)&adjTl[aRow[mi]];
    }
    {
        unsigned int u[16];
        #pragma unroll
        for (int j = 0; j < 16; ++j) {
            int kk = sb_kh * 16 + j;
            u[j] = (kk < NN) ? Xhl[(size_t)kk * COLS + cb] : 0u;
        }
        bf16x8 bh0, bh1, bl0, bl1;
        #pragma unroll
        for (int j = 0; j < 8; ++j) {
            bh0[j] = (short)(u[j] & 0xFFFFu);     bl0[j] = (short)(u[j] >> 16);
            bh1[j] = (short)(u[8 + j] & 0xFFFFu); bl1[j] = (short)(u[8 + j] >> 16);
        }
        char* rbH = (char*)Bh[0] + sb_c * 80;
        char* rbL = (char*)Bl[0] + sb_c * 80;
        int kb0 = swz_k(sb_c, sb_kh * 32);
        int kb1 = swz_k(sb_c, sb_kh * 32 + 16);
        *(bf16x8*)(rbH + kb0) = bh0; *(bf16x8*)(rbH + kb1) = bh1;
        *(bf16x8*)(rbL + kb0) = bl0; *(bf16x8*)(rbL + kb1) = bl1;
    }
    __syncthreads();

    for (int kc = 0; kc < 16; ++kc) {
        const int cur = kc & 1;
        // ---- (1) issue next-chunk B global loads into registers
        unsigned int nu[16];
        // ---- (2) issue next-chunk A fragment loads into registers
        bf16x8 ahN[4], alN[4];
        if (kc < 15) {
            const int k0n = (kc + 1) * 32;
            #pragma unroll
            for (int j = 0; j < 16; ++j) {
                int kk = k0n + sb_kh * 16 + j;
                nu[j] = (kk < NN) ? Xhl[(size_t)kk * COLS + cb] : 0u;
            }
            #pragma unroll
            for (int mi = 0; mi < 4; ++mi) {
                ahN[mi] = *(const bf16x8*)&adjTh[aRow[mi] + k0n];
                alN[mi] = *(const bf16x8*)&adjTl[aRow[mi] + k0n];
            }
        }
        // ---- (3) compute current chunk: A from regs, B from LDS buf cur
        #pragma unroll
        for (int ci = 0; ci < 4; ++ci) {
            int row = wc + ci * 16 + r16;
            int kb = swz_k(row, q * 16);
            bf16x8 bh = *(const bf16x8*)((const char*)Bh[cur] + row * 80 + kb);
            bf16x8 bl = *(const bf16x8*)((const char*)Bl[cur] + row * 80 + kb);
            #pragma unroll
            for (int mi = 0; mi < 4; ++mi) {
                acc[mi][ci] = __builtin_amdgcn_mfma_f32_16x16x32_bf16(ahC[mi], bh, acc[mi][ci], 0, 0, 0);
                acc[mi][ci] = __builtin_amdgcn_mfma_f32_16x16x32_bf16(ahC[mi], bl, acc[mi][ci], 0, 0, 0);
                acc[mi][ci] = __builtin_amdgcn_mfma_f32_16x16x32_bf16(alC[mi], bh, acc[mi][ci], 0, 0, 0);
            }
        }
        // ---- (4) write next B chunk into buf cur^1; rotate A registers
        if (kc < 15) {
            const int nb = cur ^ 1;
            bf16x8 bh0, bh1, bl0, bl1;
            #pragma unroll
            for (int j = 0; j < 8; ++j) {
                bh0[j] = (short)(nu[j] & 0xFFFFu);     bl0[j] = (short)(nu[j] >> 16);
                bh1[j] = (short)(nu[8 + j] & 0xFFFFu); bl1[j] = (short)(nu[8 + j] >> 16);
            }
            char* rbH = (char*)Bh[nb] + sb_c * 80;
            char* rbL = (char*)Bl[nb] + sb_c * 80;
            int kb0 = swz_k(sb_c, sb_kh * 32);
            int kb1 = swz_k(sb_c, sb_kh * 32 + 16);
            *(bf16x8*)(rbH + kb0) = bh0; *(bf16x8*)(rbH + kb1) = bh1;
            *(bf16x8*)(rbL + kb0) = bl0; *(bf16x8*)(rbL + kb1) = bl1;
            #pragma unroll
            for (int mi = 0; mi < 4; ++mi) { ahC[mi] = ahN[mi]; alC[mi] = alN[mi]; }
        }
        // ---- (5) single barrier per chunk
        __syncthreads();
    }

    // ---- epilogue: residual + store packed
    #pragma unroll
    for (int mi = 0; mi < 4; ++mi) {
        #pragma unroll
        for (int r = 0; r < 4; ++r) {
            int m = m0 + wm + mi * 16 + q * 4 + r;
            if (m < NN) {
                #pragma unroll
                for (int ci = 0; ci < 4; ++ci) {
                    size_t idx = (size_t)m * COLS + c0 + wc + ci * 16 + r16;
                    float y = acc[mi][ci][r] + unpack_val(Xhl[idx]);
                    Yhl[idx] = pack_hl(y);
                }
            }
        }
    }
}

// ---------------------------------------------------------------- h + LN, streaming MFMA (no LDS, no barriers, in-place)
__global__ __launch_bounds__(256)
void hln_stream_kernel(unsigned int* __restrict__ Xio,
                       const short* __restrict__ Wh, const short* __restrict__ Wl,
                       const float* __restrict__ glb, const float* __restrict__ glg,
                       const float* __restrict__ glbe)
{
    const int tid  = threadIdx.x;
    const int lane = tid & 63;
    const int wave = tid >> 6;
    const int q = lane >> 4, r16 = lane & 15;
    const size_t row0 = (size_t)blockIdx.x * 128 + wave * 32;

    float bB2[4], bG2[4], bE2[4];
    #pragma unroll
    for (int ci = 0; ci < 4; ++ci) {
        int e = ci * 16 + r16;
        bB2[ci] = glb[e]; bG2[ci] = glg[e]; bE2[ci] = glbe[e];
    }

    f32x4 acc[2][4];
    #pragma unroll
    for (int i = 0; i < 2; ++i)
        #pragma unroll
        for (int j = 0; j < 4; ++j) acc[i][j] = (f32x4){0.f, 0.f, 0.f, 0.f};

    #pragma unroll
    for (int kh = 0; kh < 2; ++kh) {
        bf16x8 wh[4], wl[4];
        #pragma unroll
        for (int ci = 0; ci < 4; ++ci) {
            int off = (ci * 16 + r16) * 64 + kh * 32 + q * 8;
            wh[ci] = *(const bf16x8*)&Wh[off];
            wl[ci] = *(const bf16x8*)&Wl[off];
        }
        #pragma unroll
        for (int mi = 0; mi < 2; ++mi) {
            const size_t row = row0 + mi * 16 + r16;
            const unsigned int* src = &Xio[row * 64 + kh * 32 + q * 8];
            uint4 u0 = *(const uint4*)src;
            uint4 u1 = *(const uint4*)(src + 4);
            bf16x8 ah, al;
            ah[0] = (short)(u0.x & 0xFFFFu); al[0] = (short)(u0.x >> 16);
            ah[1] = (short)(u0.y & 0xFFFFu); al[1] = (short)(u0.y >> 16);
            ah[2] = (short)(u0.z & 0xFFFFu); al[2] = (short)(u0.z >> 16);
            ah[3] = (short)(u0.w & 0xFFFFu); al[3] = (short)(u0.w >> 16);
            ah[4] = (short)(u1.x & 0xFFFFu); al[4] = (short)(u1.x >> 16);
            ah[5] = (short)(u1.y & 0xFFFFu); al[5] = (short)(u1.y >> 16);
            ah[6] = (short)(u1.z & 0xFFFFu); al[6] = (short)(u1.z >> 16);
            ah[7] = (short)(u1.w & 0xFFFFu); al[7] = (short)(u1.w >> 16);
            #pragma unroll
            for (int ci = 0; ci < 4; ++ci) {
                acc[mi][ci] = __builtin_amdgcn_mfma_f32_16x16x32_bf16(ah, wh[ci], acc[mi][ci], 0, 0, 0);
                acc[mi][ci] = __builtin_amdgcn_mfma_f32_16x16x32_bf16(ah, wl[ci], acc[mi][ci], 0, 0, 0);
                acc[mi][ci] = __builtin_amdgcn_mfma_f32_16x16x32_bf16(al, wh[ci], acc[mi][ci], 0, 0, 0);
            }
        }
    }

    #pragma unroll
    for (int mi = 0; mi < 2; ++mi) {
        #pragma unroll
        for (int rg = 0; rg < 4; ++rg) {
            float h[4];
            float s1 = 0.f;
            #pragma unroll
            for (int ci = 0; ci < 4; ++ci) {
                h[ci] = gelu_f(acc[mi][ci][rg] + bB2[ci]);
                s1 += h[ci];
            }
            #pragma unroll
            for (int off = 1; off < 16; off <<= 1) s1 += __shfl_xor(s1, off);
            float mu = s1 * (1.f / 64.f);
            float s2 = 0.f;
            #pragma unroll
            for (int ci = 0; ci < 4; ++ci) { float dc = h[ci] - mu; s2 += dc * dc; }
            #pragma unroll
            for (int off = 1; off < 16; off <<= 1) s2 += __shfl_xor(s2, off);
            float rs = 1.f / sqrtf(s2 * (1.f / 64.f) + 1e-5f);
            size_t grow = row0 + mi * 16 + q * 4 + rg;
            #pragma unroll
            for (int ci = 0; ci < 4; ++ci) {
                float y = (h[ci] - mu) * rs * bG2[ci] + bE2[ci];
                Xio[grow * 64 + ci * 16 + r16] = pack_hl(y);
            }
        }
    }
}

// ---------------------------------------------------------------- Wih split-convert
__global__ __launch_bounds__(256)
void wconv_kernel(const float* __restrict__ W0, const float* __restrict__ W1,
                  const float* __restrict__ W2,
                  short* __restrict__ h0, short* __restrict__ l0,
                  short* __restrict__ h1, short* __restrict__ l1,
                  short* __restrict__ h2, short* __restrict__ l2)
{
    const int gi = blockIdx.y;
    const float* W = (gi == 0) ? W0 : (gi == 1) ? W1 : W2;
    short* H = (gi == 0) ? h0 : (gi == 1) ? h1 : h2;
    short* L = (gi == 0) ? l0 : (gi == 1) ? l1 : l2;
    const size_t i = ((size_t)blockIdx.x * 256 + threadIdx.x) * 4;
    float4 v = *(const float4*)&W[i];
    short4 h4, l4;
    split4(v, h4, l4);
    *(short4*)&H[i] = h4;
    *(short4*)&L[i] = l4;
}

// ---------------------------------------------------------------- GRU pre-GEMM (MFMA)
// blocks: [0,40)=s ks; [40,120)=m; [120,760)=l.  ks-major within each GRU so
// blocks sharing a W k-slice are 40 apart (40%8==0 -> same XCD -> L2-hot W).
__global__ __launch_bounds__(256)
void gru_pre_mfma_kernel(const unsigned int* __restrict__ Xhl,
                         const short* __restrict__ Wh0, const short* __restrict__ Wl0,
                         const short* __restrict__ Wh1, const short* __restrict__ Wl1,
                         const short* __restrict__ Wh2, const short* __restrict__ Wl2,
                         float* __restrict__ p0, float* __restrict__ p1,
                         float* __restrict__ p2)
{
    __shared__ __align__(16) short Ah[64 * 40];
    __shared__ __align__(16) short Al[64 * 40];
    __shared__ __align__(16) short Bh[192 * 40];
    __shared__ __align__(16) short Bl[192 * 40];

    const int bid = blockIdx.x;
    int gi, mtid, ks;
    if (bid < 40)       { gi = 0; mtid = 0;             ks = bid; }
    else if (bid < 120) { int r = bid - 40;  gi = 1; ks = r % 40; mtid = r / 40; }
    else                { int r = bid - 120; gi = 2; ks = r % 40; mtid = r / 40; }
    const short* Wh = (gi == 0) ? Wh0 : (gi == 1) ? Wh1 : Wh2;
    const short* Wl = (gi == 0) ? Wl0 : (gi == 1) ? Wl1 : Wl2;
    float* partial  = (gi == 0) ? p0 : (gi == 1) ? p1 : p2;
    const int Trows = (gi == 0) ? 10 : (gi == 1) ? 20 : 256;
    const int toff  = (gi == 0) ? 246 : (gi == 1) ? 236 : 0;
    const int M     = (gi == 0) ? 40 : (gi == 1) ? 80 : 1024;
    const int R0 = mtid * 64;

    const int tid  = threadIdx.x;
    const int lane = tid & 63;
    const int wave = tid >> 6;
    const int wr = (wave & 1) * 32;
    const int wg = (wave >> 1) * 96;
    const int q = lane >> 4, r16 = lane & 15;

    const int sa_r = tid >> 2, sa_kq = tid & 3;
    const bool vldA = (R0 + sa_r < M);
    int btA = 0;
    if (vldA) { int R = R0 + sa_r; int b = R / Trows, t = R - b * Trows; btA = b * 256 + toff + t; }

    f32x4 acc[2][6];
    #pragma unroll
    for (int i = 0; i < 2; ++i)
        #pragma unroll
        for (int j = 0; j < 6; ++j) acc[i][j] = (f32x4){0.f, 0.f, 0.f, 0.f};

    for (int c = 0; c < KSL / 32; ++c) {
        const int k0 = ks * KSL + c * 32;
        {
            const int kk = k0 + sa_kq * 8;
            const int nn = kk >> 6, d0 = kk & 63;
            uint4 u0 = make_uint4(0u, 0u, 0u, 0u), u1 = u0;
            if (vldA) {
                const unsigned int* src = &Xhl[((size_t)nn * BS_TOT + btA) * 64 + d0];
                u0 = *(const uint4*)src;
                u1 = *(const uint4*)(src + 4);
            }
            short4 h0 = make_short4((short)(u0.x & 0xFFFF), (short)(u0.y & 0xFFFF),
                                    (short)(u0.z & 0xFFFF), (short)(u0.w & 0xFFFF));
            short4 l0 = make_short4((short)(u0.x >> 16), (short)(u0.y >> 16),
                                    (short)(u0.z >> 16), (short)(u0.w >> 16));
            short4 h1 = make_short4((short)(u1.x & 0xFFFF), (short)(u1.y & 0xFFFF),
                                    (short)(u1.z & 0xFFFF), (short)(u1.w & 0xFFFF));
            short4 l1 = make_short4((short)(u1.x >> 16), (short)(u1.y >> 16),
                                    (short)(u1.z >> 16), (short)(u1.w >> 16));
            int kb = swz_k(sa_r, sa_kq * 16);
            char* rowH = (char*)Ah + sa_r * 80;
            char* rowL = (char*)Al + sa_r * 80;
            *(short4*)(rowH + kb) = h0; *(short4*)(rowH + kb + 8) = h1;
            *(short4*)(rowL + kb) = l0; *(short4*)(rowL + kb + 8) = l1;
        }
        #pragma unroll
        for (int l = 0; l < 3; ++l) {
            int idx = tid + l * 256;
            int g = idx >> 2, kq = idx & 3;
            const size_t src = (size_t)g * I_DIM + k0 + kq * 8;
            bf16x8 hv = *(const bf16x8*)&Wh[src];
            bf16x8 lv = *(const bf16x8*)&Wl[src];
            int kb = swz_k(g, kq * 16);
            *(bf16x8*)((char*)Bh + g * 80 + kb) = hv;
            *(bf16x8*)((char*)Bl + g * 80 + kb) = lv;
        }
        __syncthreads();
        bf16x8 ah[2], al[2];
        #pragma unroll
        for (int mi = 0; mi < 2; ++mi) {
            int row = wr + mi * 16 + r16;
            int kb = swz_k(row, q * 16);
            ah[mi] = *(const bf16x8*)((const char*)Ah + row * 80 + kb);
            al[mi] = *(const bf16x8*)((const char*)Al + row * 80 + kb);
        }
        #pragma unroll
        for (int ci = 0; ci < 6; ++ci) {
            int grow = wg + ci * 16 + r16;
            int kb = swz_k(grow, q * 16);
            bf16x8 bh = *(const bf16x8*)((const char*)Bh + grow * 80 + kb);
            bf16x8 bl = *(const bf16x8*)((const char*)Bl + grow * 80 + kb);
            #pragma unroll
            for (int mi = 0; mi < 2; ++mi) {
                acc[mi][ci] = __builtin_amdgcn_mfma_f32_16x16x32_bf16(ah[mi], bh, acc[mi][ci], 0, 0, 0);
                acc[mi][ci] = __builtin_amdgcn_mfma_f32_16x16x32_bf16(ah[mi], bl, acc[mi][ci], 0, 0, 0);
                acc[mi][ci] = __builtin_amdgcn_mfma_f32_16x16x32_bf16(al[mi], bh, acc[mi][ci], 0, 0, 0);
            }
        }
        __syncthreads();
    }
    #pragma unroll
    for (int mi = 0; mi < 2; ++mi) {
        #pragma unroll
        for (int r = 0; r < 4; ++r) {
            int R = R0 + wr + mi * 16 + q * 4 + r;
            if (R < M) {
                #pragma unroll
                for (int ci = 0; ci < 6; ++ci)
                    partial[((size_t)ks * M + R) * 192 + wg + ci * 16 + r16] = acc[mi][ci][r];
            }
        }
    }
}

// ---------------------------------------------------------------- reduce (all 3 fused)
__global__ __launch_bounds__(192)
void gru_reduce_fused_kernel(const float* __restrict__ p0, const float* __restrict__ p1,
                             const float* __restrict__ p2,
                             const float* __restrict__ bih0, const float* __restrict__ bih1,
                             const float* __restrict__ bih2,
                             float* __restrict__ xp0, float* __restrict__ xp1,
                             float* __restrict__ xp2)
{
    int r = blockIdx.x;
    const float* partial; const float* bih; float* xp; int M;
    if (r < 40)       { partial = p0; bih = bih0; xp = xp0; M = 40; }
    else if (r < 120) { r -= 40;  partial = p1; bih = bih1; xp = xp1; M = 80; }
    else              { r -= 120; partial = p2; bih = bih2; xp = xp2; M = 1024; }
    const int g = threadIdx.x;
    float acc = bih[g];
    for (int ks = 0; ks < KS_GRU; ++ks)
        acc += partial[((size_t)ks * M + r) * 192 + g];
    xp[(size_t)r * 192 + g] = acc;
}

// ---------------------------------------------------------------- GRU scan
__global__ __launch_bounds__(192)
void gru_scan_kernel(const float* __restrict__ xp_s, const float* __restrict__ xp_m,
                     const float* __restrict__ xp_l,
                     const float* __restrict__ Whh_s, const float* __restrict__ Whh_m,
                     const float* __restrict__ Whh_l,
                     const float* __restrict__ bhh_s, const float* __restrict__ bhh_m,
                     const float* __restrict__ bhh_l,
                     float* __restrict__ hcat)
{
    __shared__ float h[64];
    __shared__ float gh[192];
    const int blk = blockIdx.x;
    const int g3 = blk >> 2, b = blk & 3;
    const float* xp  = (g3 == 0) ? xp_s : (g3 == 1) ? xp_m : xp_l;
    const float* Whh = (g3 == 0) ? Whh_s : (g3 == 1) ? Whh_m : Whh_l;
    const float* bhh = (g3 == 0) ? bhh_s : (g3 == 1) ? bhh_m : bhh_l;
    const int T = (g3 == 0) ? 10 : (g3 == 1) ? 20 : 256;
    const int g = threadIdx.x;

    float w[64];
    #pragma unroll
    for (int k4 = 0; k4 < 16; ++k4) {
        float4 v = *(const float4*)&Whh[g * 64 + k4 * 4];
        w[k4 * 4 + 0] = v.x; w[k4 * 4 + 1] = v.y;
        w[k4 * 4 + 2] = v.z; w[k4 * 4 + 3] = v.w;
    }
    const float bh = bhh[g];
    if (g < 64) h[g] = 0.f;

    const float* xpb = xp + (size_t)b * T * 192;
    float xr_c = 0.f, xz_c = 0.f, xn_c = 0.f;
    if (g < 64) { xr_c = xpb[g]; xz_c = xpb[64 + g]; xn_c = xpb[128 + g]; }
    __syncthreads();

    for (int t = 0; t < T; ++t) {
        float xr_n = 0.f, xz_n = 0.f, xn_n = 0.f;
        if (t + 1 < T && g < 64) {
            const float* xq = xpb + (size_t)(t + 1) * 192;
            xr_n = xq[g]; xz_n = xq[64 + g]; xn_n = xq[128 + g];
        }
        float a0 = 0.f, a1 = 0.f, a2 = 0.f, a3 = 0.f;
        #pragma unroll
        for (int k4 = 0; k4 < 16; ++k4) {
            float4 hv = ((const float4*)h)[k4];
            a0 += hv.x * w[k4 * 4 + 0];
            a1 += hv.y * w[k4 * 4 + 1];
            a2 += hv.z * w[k4 * 4 + 2];
            a3 += hv.w * w[k4 * 4 + 3];
        }
        gh[g] = bh + ((a0 + a1) + (a2 + a3));
        __syncthreads();
        if (g < 64) {
            float hr = gh[g], hz = gh[64 + g], hn = gh[128 + g];
            float r = 1.f / (1.f + __expf(-(xr_c + hr)));
            float z = 1.f / (1.f + __expf(-(xz_c + hz)));
            float pre = xn_c + r * hn;
            float e2 = __expf(2.f * pre);
            float nv = 1.f - 2.f / (e2 + 1.f);   // tanh
            h[g] = (1.f - z) * nv + z * h[g];
        }
        __syncthreads();
        xr_c = xr_n; xz_c = xz_n; xn_c = xn_n;
    }
    if (g < 64) hcat[b * 192 + g3 * 64 + g] = h[g];
}

// ---------------------------------------------------------------- head
__global__ __launch_bounds__(512)
void head_kernel(const float* __restrict__ hcat,
                 const float* __restrict__ W1, const float* __restrict__ b1,
                 const float* __restrict__ W2, const float* __restrict__ b2,
                 float* __restrict__ out)
{
    __shared__ float hc[4][192];
    __shared__ float h1[4][64];
    const int tid = threadIdx.x;
    for (int i = tid; i < 768; i += 512) hc[i / 192][i % 192] = hcat[i];
    __syncthreads();
    if (tid < 256) {
        int b = tid >> 6, e = tid & 63;
        float acc = b1[e];
        #pragma unroll
        for (int k = 0; k < 192; ++k) acc += hc[b][k] * W1[e * 192 + k];
        h1[b][e] = gelu_f(acc);
    }
    __syncthreads();
    for (int o = tid; o < 2000; o += 512) {
        int b = o / 500, n = o % 500;
        float acc = b2[n];
        #pragma unroll
        for (int k = 0; k < 64; ++k) acc += h1[b][k] * W2[n * 64 + k];
        out[o] = acc;
    }
}

// ================================================================ launch
extern "C" void kernel_launch(void* const* d_in, const int* in_sizes, int n_in,
                              void* d_out, int out_size, void* d_ws, size_t ws_size,
                              hipStream_t stream)
{
    (void)in_sizes; (void)n_in; (void)out_size; (void)ws_size;
    const float* x    = (const float*)d_in[0];
    const float* ipW  = (const float*)d_in[1];
    const float* ipb  = (const float*)d_in[2];
    const float* fe   = (const float*)d_in[3];
    const float* te   = (const float*)d_in[4];
    const float* glW  = (const float*)d_in[5];
    const float* glb  = (const float*)d_in[6];
    const float* glg  = (const float*)d_in[7];
    const float* glbe = (const float*)d_in[8];
    const float* Wih[3] = {(const float*)d_in[9],  (const float*)d_in[13], (const float*)d_in[17]};
    const float* Whh[3] = {(const float*)d_in[10], (const float*)d_in[14], (const float*)d_in[18]};
    const float* bih[3] = {(const float*)d_in[11], (const float*)d_in[15], (const float*)d_in[19]};
    const float* bhh[3] = {(const float*)d_in[12], (const float*)d_in[16], (const float*)d_in[20]};
    const float* W1 = (const float*)d_in[21];
    const float* b1 = (const float*)d_in[22];
    const float* W2 = (const float*)d_in[23];
    const float* b2 = (const float*)d_in[24];
    float* out = (float*)d_out;

    unsigned int* Xhl = (unsigned int*)d_ws;          // 32,768,000 uints (131 MB)
    unsigned int* Yhl = Xhl + 32768000;               // 32,768,000 uints (131 MB)
    short* adjTh = (short*)(Yhl + 32768000);          // 512*512 shorts
    short* adjTl = adjTh + NPAD * NPAD;
    short* glWh  = adjTl + NPAD * NPAD;               // 8192 shorts (2 layers)
    short* glWl  = glWh + 8192;
    short* ipWh  = glWl + 8192;                       // 2048 shorts
    short* ipWl  = ipWh + 2048;
    // GRU-phase scratch overlays Yhl (dead after layer-2):
    short* wbase = (short*)Yhl;
    short* Wh0 = wbase;                               // 6,144,000 shorts each
    short* Wl0 = Wh0 + 6144000;
    short* Wh1 = Wl0 + 6144000;
    short* Wl1 = Wh1 + 6144000;
    short* Wh2 = Wl1 + 6144000;
    short* Wl2 = Wh2 + 6144000;
    float* pbase = (float*)Yhl + 18432000;
    float* part0 = pbase;                             // 40*40*192   = 307,200
    float* part1 = part0 + 307200;                    // 40*80*192   = 614,400
    float* part2 = part1 + 614400;                    // 40*1024*192 = 7,864,320
    float* xp0   = part2 + 7864320;                   // 7,680
    float* xp1   = xp0 + 7680;                        // 15,360
    float* xp2   = xp1 + 15360;                       // 196,608
    float* hcat  = xp2 + 196608;                      // 768

    hipMemsetAsync(adjTh, 0, (size_t)NPAD * NPAD * 2 * sizeof(short), stream);
    adj_kernel<<<NN, 512, 0, stream>>>(fe, te, adjTh, adjTl);
    wsplit_kernel<<<8, 256, 0, stream>>>(glW, glWh, glWl, 2048);
    wsplit_kernel<<<2, 256, 0, stream>>>(ipW, ipWh, ipWl, 512);
    proj_mfma_kernel<<<4000, 256, 0, stream>>>(x, ipWh, ipWl, ipb, Xhl);

    // layer 1: Xhl -> Yhl (agg+residual), then h+LN in-place on Yhl
    agg_mfma_kernel<<<dim3(512, 4), 256, 0, stream>>>(Xhl, adjTh, adjTl, Yhl);
    hln_stream_kernel<<<4000, 256, 0, stream>>>(Yhl, glWh, glWl, glb, glg, glbe);
    // layer 2: Yhl -> Xhl, then in-place on Xhl
    agg_mfma_kernel<<<dim3(512, 4), 256, 0, stream>>>(Yhl, adjTh, adjTl, Xhl);
    hln_stream_kernel<<<4000, 256, 0, stream>>>(Xhl, glWh + 4096, glWl + 4096,
                                                glb + 64, glg + 64, glbe + 64);

    wconv_kernel<<<dim3(6000, 3), 256, 0, stream>>>(Wih[0], Wih[1], Wih[2],
                                                    Wh0, Wl0, Wh1, Wl1, Wh2, Wl2);
    gru_pre_mfma_kernel<<<760, 256, 0, stream>>>(Xhl, Wh0, Wl0, Wh1, Wl1, Wh2, Wl2,
                                                 part0, part1, part2);
    gru_reduce_fused_kernel<<<1144, 192, 0, stream>>>(part0, part1, part2,
                                                      bih[0], bih[1], bih[2],
                                                      xp0, xp1, xp2);
    gru_scan_kernel<<<12, 192, 0, stream>>>(xp0, xp1, xp2,
                                            Whh[0], Whh[1], Whh[2],
                                            bhh[0], bhh[1], bhh[2], hcat);
    head_kernel<<<1, 512, 0, stream>>>(hcat, W1, b1, W2, b2, out);
}

// Round 15
// 792.143 us; speedup vs baseline: 1.1238x; 1.0931x over previous
//
#include <hip/hip_runtime.h>
#include <math.h>

#define NN 500
#define DD 64
#define NPAD 512             // adjT padded to [512][512]
#define COLS 65536           // 1024 * 64
#define BS_TOT 1024          // B*S
#define I_DIM 32000          // N*D
#define KS_GRU 40            // K-split for GRU pre-GEMM
#define KSL 800              // 32000/40

typedef __attribute__((ext_vector_type(8))) short bf16x8;
typedef __attribute__((ext_vector_type(4))) float f32x4;

__device__ __forceinline__ float gelu_f(float x) {
    return 0.5f * x * (1.0f + erff(x * 0.70710678118654752440f));
}

__device__ __forceinline__ unsigned short bf16_rn(float x) {
    unsigned int u = __float_as_uint(x);
    unsigned int r = u + 0x7FFFu + ((u >> 16) & 1u);
    return (unsigned short)(r >> 16);
}
__device__ __forceinline__ float bf16_tof(unsigned short h) {
    return __uint_as_float(((unsigned int)h) << 16);
}
// packed split-bf16: u = hi | (lo<<16); value = tof(hi)+tof(lo)
__device__ __forceinline__ unsigned int pack_hl(float x) {
    unsigned short h = bf16_rn(x);
    unsigned short l = bf16_rn(x - bf16_tof(h));
    return (unsigned int)h | ((unsigned int)l << 16);
}
__device__ __forceinline__ float unpack_val(unsigned int u) {
    return __uint_as_float(u << 16) + __uint_as_float(u & 0xFFFF0000u);
}
__device__ __forceinline__ void split4(float4 v, short4& h4, short4& l4) {
    h4.x = (short)bf16_rn(v.x); l4.x = (short)bf16_rn(v.x - bf16_tof((unsigned short)h4.x));
    h4.y = (short)bf16_rn(v.y); l4.y = (short)bf16_rn(v.y - bf16_tof((unsigned short)h4.y));
    h4.z = (short)bf16_rn(v.z); l4.z = (short)bf16_rn(v.z - bf16_tof((unsigned short)h4.z));
    h4.w = (short)bf16_rn(v.w); l4.w = (short)bf16_rn(v.w - bf16_tof((unsigned short)h4.w));
}

// LDS XOR swizzle (16B granularity within 64B k-extent)
__device__ __forceinline__ int swz_k(int row, int kbyte) {
    return kbyte ^ (((row >> 3) & 3) << 4);
}

// ---------------------------------------------------------------- adjacency
__global__ __launch_bounds__(512)
void adj_kernel(const float* __restrict__ fe, const float* __restrict__ te,
                short* __restrict__ adjTh, short* __restrict__ adjTl)
{
    __shared__ float fr[32];
    __shared__ float red[8];
    __shared__ float red2[8];
    const int n = blockIdx.x;
    const int tid = threadIdx.x;
    if (tid < 32) fr[tid] = fe[n * 32 + tid];
    __syncthreads();
    const int m = tid;
    float s = -1e30f;
    if (m < NN) {
        float acc = 0.f;
        #pragma unroll
        for (int f = 0; f < 32; ++f) acc += fr[f] * te[m * 32 + f];
        s = acc * 2.0f;   // 1/TEMP
    }
    float v = s;
    #pragma unroll
    for (int off = 32; off; off >>= 1) v = fmaxf(v, __shfl_xor(v, off));
    if ((tid & 63) == 0) red[tid >> 6] = v;
    __syncthreads();
    float bmax = red[0];
    #pragma unroll
    for (int i = 1; i < 8; ++i) bmax = fmaxf(bmax, red[i]);
    float e = (m < NN) ? expf(s - bmax) : 0.f;
    float v2 = e;
    #pragma unroll
    for (int off = 32; off; off >>= 1) v2 += __shfl_xor(v2, off);
    if ((tid & 63) == 0) red2[tid >> 6] = v2;
    __syncthreads();
    float bsum = 0.f;
    #pragma unroll
    for (int i = 0; i < 8; ++i) bsum += red2[i];
    if (m < NN) {
        float p = e / bsum;
        unsigned short h = bf16_rn(p);
        adjTh[(size_t)m * NPAD + n] = (short)h;
        adjTl[(size_t)m * NPAD + n] = (short)bf16_rn(p - bf16_tof(h));
    }
}

// ---------------------------------------------------------------- generic split-convert
__global__ __launch_bounds__(256)
void wsplit_kernel(const float* __restrict__ W, short* __restrict__ H,
                   short* __restrict__ L, int n4)
{
    int i = blockIdx.x * 256 + threadIdx.x;
    if (i < n4) {
        float4 v = *(const float4*)&W[i * 4];
        short4 h4, l4;
        split4(v, h4, l4);
        *(short4*)&H[i * 4] = h4;
        *(short4*)&L[i * 4] = l4;
    }
}

// ---------------------------------------------------------------- input proj (streaming MFMA, no LDS)
__global__ __launch_bounds__(256)
void proj_mfma_kernel(const float* __restrict__ xin,
                      const short* __restrict__ Wh, const short* __restrict__ Wl,
                      const float* __restrict__ ipb, unsigned int* __restrict__ Xhl)
{
    const int tid  = threadIdx.x;
    const int lane = tid & 63;
    const int wave = tid >> 6;
    const int q = lane >> 4, r16 = lane & 15;
    const size_t row0 = (size_t)blockIdx.x * 128 + wave * 32;

    float bB[4];
    #pragma unroll
    for (int ci = 0; ci < 4; ++ci) bB[ci] = ipb[ci * 16 + r16];

    bf16x8 wh[4], wl[4];
    #pragma unroll
    for (int ci = 0; ci < 4; ++ci) {
        int off = (ci * 16 + r16) * 32 + q * 8;
        wh[ci] = *(const bf16x8*)&Wh[off];
        wl[ci] = *(const bf16x8*)&Wl[off];
    }

    f32x4 acc[2][4];
    #pragma unroll
    for (int i = 0; i < 2; ++i)
        #pragma unroll
        for (int j = 0; j < 4; ++j) acc[i][j] = (f32x4){0.f, 0.f, 0.f, 0.f};

    #pragma unroll
    for (int mi = 0; mi < 2; ++mi) {
        const size_t row = row0 + mi * 16 + r16;
        const int n = (int)(row >> 10), bs = (int)(row & 1023);
        const float* src = &xin[((size_t)bs * NN + n) * 32 + q * 8];
        float4 v0 = *(const float4*)src;
        float4 v1 = *(const float4*)(src + 4);
        short4 h0, l0, h1, l1;
        split4(v0, h0, l0);
        split4(v1, h1, l1);
        bf16x8 ah, al;
        ah[0] = h0.x; ah[1] = h0.y; ah[2] = h0.z; ah[3] = h0.w;
        ah[4] = h1.x; ah[5] = h1.y; ah[6] = h1.z; ah[7] = h1.w;
        al[0] = l0.x; al[1] = l0.y; al[2] = l0.z; al[3] = l0.w;
        al[4] = l1.x; al[5] = l1.y; al[6] = l1.z; al[7] = l1.w;
        #pragma unroll
        for (int ci = 0; ci < 4; ++ci) {
            acc[mi][ci] = __builtin_amdgcn_mfma_f32_16x16x32_bf16(ah, wh[ci], acc[mi][ci], 0, 0, 0);
            acc[mi][ci] = __builtin_amdgcn_mfma_f32_16x16x32_bf16(ah, wl[ci], acc[mi][ci], 0, 0, 0);
            acc[mi][ci] = __builtin_amdgcn_mfma_f32_16x16x32_bf16(al, wh[ci], acc[mi][ci], 0, 0, 0);
        }
    }

    #pragma unroll
    for (int mi = 0; mi < 2; ++mi) {
        #pragma unroll
        for (int rg = 0; rg < 4; ++rg) {
            size_t grow = row0 + mi * 16 + q * 4 + rg;
            #pragma unroll
            for (int ci = 0; ci < 4; ++ci) {
                float y = gelu_f(acc[mi][ci][rg] + bB[ci]);
                Xhl[grow * 64 + ci * 16 + r16] = pack_hl(y);
            }
        }
    }
}

// ---------------------------------------------------------------- agg GEMM (split-bf16 MFMA, dbuf, 2-deep B prefetch)
// C[m][c] = sum_n adjT[m][n]*X[n][c] + X[m][c]; packed in/out.
// A & B in LDS double-buffer; B's global loads issued TWO chunks ahead so a
// full iteration (~MFMA+stage) covers HBM latency before the ds_write drains.
__global__ __launch_bounds__(256)
void agg_mfma_kernel(const unsigned int* __restrict__ Xhl,
                     const short* __restrict__ adjTh, const short* __restrict__ adjTl,
                     unsigned int* __restrict__ Yhl)
{
    __shared__ __align__(16) short Ah[2][128 * 40];
    __shared__ __align__(16) short Al[2][128 * 40];
    __shared__ __align__(16) short Bh[2][128 * 40];
    __shared__ __align__(16) short Bl[2][128 * 40];

    const int tid  = threadIdx.x;
    const int lane = tid & 63;
    const int wave = tid >> 6;
    const int wm = (wave >> 1) * 64;
    const int wc = (wave & 1) * 64;
    const int q = lane >> 4, r16 = lane & 15;
    const int c0 = blockIdx.x * 128;
    const int m0 = blockIdx.y * 128;

    const int sa_m = tid >> 1, sa_kh = tid & 1;
    const int sb_c = tid & 127, sb_kh = tid >> 7;
    const size_t cb = (size_t)(c0 + sb_c);

    f32x4 acc[4][4];
    #pragma unroll
    for (int i = 0; i < 4; ++i)
        #pragma unroll
        for (int j = 0; j < 4; ++j) acc[i][j] = (f32x4){0.f, 0.f, 0.f, 0.f};

    // ---- prologue: A0 + B0 into LDS buf 0; issue B1 loads into registers
    {
        const size_t base = (size_t)(m0 + sa_m) * NPAD + sa_kh * 16;
        bf16x8 h0 = *(const bf16x8*)&adjTh[base];
        bf16x8 h1 = *(const bf16x8*)&adjTh[base + 8];
        bf16x8 l0 = *(const bf16x8*)&adjTl[base];
        bf16x8 l1 = *(const bf16x8*)&adjTl[base + 8];
        char* rowH = (char*)Ah[0] + sa_m * 80;
        char* rowL = (char*)Al[0] + sa_m * 80;
        *(bf16x8*)(rowH + swz_k(sa_m, sa_kh * 32))      = h0;
        *(bf16x8*)(rowH + swz_k(sa_m, sa_kh * 32 + 16)) = h1;
        *(bf16x8*)(rowL + swz_k(sa_m, sa_kh * 32))      = l0;
        *(bf16x8*)(rowL + swz_k(sa_m, sa_kh * 32 + 16)) = l1;

        unsigned int u[16];
        #pragma unroll
        for (int j = 0; j < 16; ++j) {
            int kk = sb_kh * 16 + j;
            u[j] = (kk < NN) ? Xhl[(size_t)kk * COLS + cb] : 0u;
        }
        bf16x8 bh0, bh1, bl0, bl1;
        #pragma unroll
        for (int j = 0; j < 8; ++j) {
            bh0[j] = (short)(u[j] & 0xFFFFu);     bl0[j] = (short)(u[j] >> 16);
            bh1[j] = (short)(u[8 + j] & 0xFFFFu); bl1[j] = (short)(u[8 + j] >> 16);
        }
        char* rbH = (char*)Bh[0] + sb_c * 80;
        char* rbL = (char*)Bl[0] + sb_c * 80;
        int kb0 = swz_k(sb_c, sb_kh * 32);
        int kb1 = swz_k(sb_c, sb_kh * 32 + 16);
        *(bf16x8*)(rbH + kb0) = bh0; *(bf16x8*)(rbH + kb1) = bh1;
        *(bf16x8*)(rbL + kb0) = bl0; *(bf16x8*)(rbL + kb1) = bl1;
    }
    unsigned int nuCur[16];
    #pragma unroll
    for (int j = 0; j < 16; ++j) {
        int kk = 32 + sb_kh * 16 + j;
        nuCur[j] = (kk < NN) ? Xhl[(size_t)kk * COLS + cb] : 0u;
    }
    __syncthreads();

    for (int kc = 0; kc < 16; ++kc) {
        const int cur = kc & 1;
        // ---- (1) issue B chunk kc+2 loads into registers (2-deep prefetch)
        unsigned int nuNext[16];
        if (kc + 2 < 16) {
            const int k0n = (kc + 2) * 32;
            #pragma unroll
            for (int j = 0; j < 16; ++j) {
                int kk = k0n + sb_kh * 16 + j;
                nuNext[j] = (kk < NN) ? Xhl[(size_t)kk * COLS + cb] : 0u;
            }
        }
        // ---- (2) issue A chunk kc+1 loads into registers
        bf16x8 nAh0, nAh1, nAl0, nAl1;
        if (kc < 15) {
            const int k0n = (kc + 1) * 32;
            const size_t base = (size_t)(m0 + sa_m) * NPAD + k0n + sa_kh * 16;
            nAh0 = *(const bf16x8*)&adjTh[base];
            nAh1 = *(const bf16x8*)&adjTh[base + 8];
            nAl0 = *(const bf16x8*)&adjTl[base];
            nAl1 = *(const bf16x8*)&adjTl[base + 8];
        }
        // ---- (3) compute current chunk from LDS buf cur
        bf16x8 ah[4], al[4];
        #pragma unroll
        for (int mi = 0; mi < 4; ++mi) {
            int row = wm + mi * 16 + r16;
            int kb = swz_k(row, q * 16);
            ah[mi] = *(const bf16x8*)((const char*)Ah[cur] + row * 80 + kb);
            al[mi] = *(const bf16x8*)((const char*)Al[cur] + row * 80 + kb);
        }
        #pragma unroll
        for (int ci = 0; ci < 4; ++ci) {
            int row = wc + ci * 16 + r16;
            int kb = swz_k(row, q * 16);
            bf16x8 bh = *(const bf16x8*)((const char*)Bh[cur] + row * 80 + kb);
            bf16x8 bl = *(const bf16x8*)((const char*)Bl[cur] + row * 80 + kb);
            #pragma unroll
            for (int mi = 0; mi < 4; ++mi) {
                acc[mi][ci] = __builtin_amdgcn_mfma_f32_16x16x32_bf16(ah[mi], bh, acc[mi][ci], 0, 0, 0);
                acc[mi][ci] = __builtin_amdgcn_mfma_f32_16x16x32_bf16(ah[mi], bl, acc[mi][ci], 0, 0, 0);
                acc[mi][ci] = __builtin_amdgcn_mfma_f32_16x16x32_bf16(al[mi], bh, acc[mi][ci], 0, 0, 0);
            }
        }
        // ---- (4) write chunk kc+1 (B from nuCur regs, issued a full iter ago; A from nA regs)
        if (kc < 15) {
            const int nb = cur ^ 1;
            char* rowH = (char*)Ah[nb] + sa_m * 80;
            char* rowL = (char*)Al[nb] + sa_m * 80;
            *(bf16x8*)(rowH + swz_k(sa_m, sa_kh * 32))      = nAh0;
            *(bf16x8*)(rowH + swz_k(sa_m, sa_kh * 32 + 16)) = nAh1;
            *(bf16x8*)(rowL + swz_k(sa_m, sa_kh * 32))      = nAl0;
            *(bf16x8*)(rowL + swz_k(sa_m, sa_kh * 32 + 16)) = nAl1;
            bf16x8 bh0, bh1, bl0, bl1;
            #pragma unroll
            for (int j = 0; j < 8; ++j) {
                bh0[j] = (short)(nuCur[j] & 0xFFFFu);     bl0[j] = (short)(nuCur[j] >> 16);
                bh1[j] = (short)(nuCur[8 + j] & 0xFFFFu); bl1[j] = (short)(nuCur[8 + j] >> 16);
            }
            char* rbH = (char*)Bh[nb] + sb_c * 80;
            char* rbL = (char*)Bl[nb] + sb_c * 80;
            int kb0 = swz_k(sb_c, sb_kh * 32);
            int kb1 = swz_k(sb_c, sb_kh * 32 + 16);
            *(bf16x8*)(rbH + kb0) = bh0; *(bf16x8*)(rbH + kb1) = bh1;
            *(bf16x8*)(rbL + kb0) = bl0; *(bf16x8*)(rbL + kb1) = bl1;
        }
        // ---- (5) rotate B register pipeline
        if (kc + 2 < 16) {
            #pragma unroll
            for (int j = 0; j < 16; ++j) nuCur[j] = nuNext[j];
        }
        // ---- (6) single barrier per chunk
        __syncthreads();
    }

    // ---- epilogue: residual + store packed
    #pragma unroll
    for (int mi = 0; mi < 4; ++mi) {
        #pragma unroll
        for (int r = 0; r < 4; ++r) {
            int m = m0 + wm + mi * 16 + q * 4 + r;
            if (m < NN) {
                #pragma unroll
                for (int ci = 0; ci < 4; ++ci) {
                    size_t idx = (size_t)m * COLS + c0 + wc + ci * 16 + r16;
                    float y = acc[mi][ci][r] + unpack_val(Xhl[idx]);
                    Yhl[idx] = pack_hl(y);
                }
            }
        }
    }
}

// ---------------------------------------------------------------- h + LN, streaming MFMA (no LDS, no barriers, in-place)
__global__ __launch_bounds__(256)
void hln_stream_kernel(unsigned int* __restrict__ Xio,
                       const short* __restrict__ Wh, const short* __restrict__ Wl,
                       const float* __restrict__ glb, const float* __restrict__ glg,
                       const float* __restrict__ glbe)
{
    const int tid  = threadIdx.x;
    const int lane = tid & 63;
    const int wave = tid >> 6;
    const int q = lane >> 4, r16 = lane & 15;
    const size_t row0 = (size_t)blockIdx.x * 128 + wave * 32;

    float bB2[4], bG2[4], bE2[4];
    #pragma unroll
    for (int ci = 0; ci < 4; ++ci) {
        int e = ci * 16 + r16;
        bB2[ci] = glb[e]; bG2[ci] = glg[e]; bE2[ci] = glbe[e];
    }

    f32x4 acc[2][4];
    #pragma unroll
    for (int i = 0; i < 2; ++i)
        #pragma unroll
        for (int j = 0; j < 4; ++j) acc[i][j] = (f32x4){0.f, 0.f, 0.f, 0.f};

    #pragma unroll
    for (int kh = 0; kh < 2; ++kh) {
        bf16x8 wh[4], wl[4];
        #pragma unroll
        for (int ci = 0; ci < 4; ++ci) {
            int off = (ci * 16 + r16) * 64 + kh * 32 + q * 8;
            wh[ci] = *(const bf16x8*)&Wh[off];
            wl[ci] = *(const bf16x8*)&Wl[off];
        }
        #pragma unroll
        for (int mi = 0; mi < 2; ++mi) {
            const size_t row = row0 + mi * 16 + r16;
            const unsigned int* src = &Xio[row * 64 + kh * 32 + q * 8];
            uint4 u0 = *(const uint4*)src;
            uint4 u1 = *(const uint4*)(src + 4);
            bf16x8 ah, al;
            ah[0] = (short)(u0.x & 0xFFFFu); al[0] = (short)(u0.x >> 16);
            ah[1] = (short)(u0.y & 0xFFFFu); al[1] = (short)(u0.y >> 16);
            ah[2] = (short)(u0.z & 0xFFFFu); al[2] = (short)(u0.z >> 16);
            ah[3] = (short)(u0.w & 0xFFFFu); al[3] = (short)(u0.w >> 16);
            ah[4] = (short)(u1.x & 0xFFFFu); al[4] = (short)(u1.x >> 16);
            ah[5] = (short)(u1.y & 0xFFFFu); al[5] = (short)(u1.y >> 16);
            ah[6] = (short)(u1.z & 0xFFFFu); al[6] = (short)(u1.z >> 16);
            ah[7] = (short)(u1.w & 0xFFFFu); al[7] = (short)(u1.w >> 16);
            #pragma unroll
            for (int ci = 0; ci < 4; ++ci) {
                acc[mi][ci] = __builtin_amdgcn_mfma_f32_16x16x32_bf16(ah, wh[ci], acc[mi][ci], 0, 0, 0);
                acc[mi][ci] = __builtin_amdgcn_mfma_f32_16x16x32_bf16(ah, wl[ci], acc[mi][ci], 0, 0, 0);
                acc[mi][ci] = __builtin_amdgcn_mfma_f32_16x16x32_bf16(al, wh[ci], acc[mi][ci], 0, 0, 0);
            }
        }
    }

    #pragma unroll
    for (int mi = 0; mi < 2; ++mi) {
        #pragma unroll
        for (int rg = 0; rg < 4; ++rg) {
            float h[4];
            float s1 = 0.f;
            #pragma unroll
            for (int ci = 0; ci < 4; ++ci) {
                h[ci] = gelu_f(acc[mi][ci][rg] + bB2[ci]);
                s1 += h[ci];
            }
            #pragma unroll
            for (int off = 1; off < 16; off <<= 1) s1 += __shfl_xor(s1, off);
            float mu = s1 * (1.f / 64.f);
            float s2 = 0.f;
            #pragma unroll
            for (int ci = 0; ci < 4; ++ci) { float dc = h[ci] - mu; s2 += dc * dc; }
            #pragma unroll
            for (int off = 1; off < 16; off <<= 1) s2 += __shfl_xor(s2, off);
            float rs = 1.f / sqrtf(s2 * (1.f / 64.f) + 1e-5f);
            size_t grow = row0 + mi * 16 + q * 4 + rg;
            #pragma unroll
            for (int ci = 0; ci < 4; ++ci) {
                float y = (h[ci] - mu) * rs * bG2[ci] + bE2[ci];
                Xio[grow * 64 + ci * 16 + r16] = pack_hl(y);
            }
        }
    }
}

// ---------------------------------------------------------------- Wih split-convert
__global__ __launch_bounds__(256)
void wconv_kernel(const float* __restrict__ W0, const float* __restrict__ W1,
                  const float* __restrict__ W2,
                  short* __restrict__ h0, short* __restrict__ l0,
                  short* __restrict__ h1, short* __restrict__ l1,
                  short* __restrict__ h2, short* __restrict__ l2)
{
    const int gi = blockIdx.y;
    const float* W = (gi == 0) ? W0 : (gi == 1) ? W1 : W2;
    short* H = (gi == 0) ? h0 : (gi == 1) ? h1 : h2;
    short* L = (gi == 0) ? l0 : (gi == 1) ? l1 : l2;
    const size_t i = ((size_t)blockIdx.x * 256 + threadIdx.x) * 4;
    float4 v = *(const float4*)&W[i];
    short4 h4, l4;
    split4(v, h4, l4);
    *(short4*)&H[i] = h4;
    *(short4*)&L[i] = l4;
}

// ---------------------------------------------------------------- GRU pre-GEMM (MFMA)
// blocks: [0,40)=s ks; [40,120)=m; [120,760)=l.  ks-major within each GRU so
// blocks sharing a W k-slice are 40 apart (40%8==0 -> same XCD -> L2-hot W).
__global__ __launch_bounds__(256)
void gru_pre_mfma_kernel(const unsigned int* __restrict__ Xhl,
                         const short* __restrict__ Wh0, const short* __restrict__ Wl0,
                         const short* __restrict__ Wh1, const short* __restrict__ Wl1,
                         const short* __restrict__ Wh2, const short* __restrict__ Wl2,
                         float* __restrict__ p0, float* __restrict__ p1,
                         float* __restrict__ p2)
{
    __shared__ __align__(16) short Ah[64 * 40];
    __shared__ __align__(16) short Al[64 * 40];
    __shared__ __align__(16) short Bh[192 * 40];
    __shared__ __align__(16) short Bl[192 * 40];

    const int bid = blockIdx.x;
    int gi, mtid, ks;
    if (bid < 40)       { gi = 0; mtid = 0;             ks = bid; }
    else if (bid < 120) { int r = bid - 40;  gi = 1; ks = r % 40; mtid = r / 40; }
    else                { int r = bid - 120; gi = 2; ks = r % 40; mtid = r / 40; }
    const short* Wh = (gi == 0) ? Wh0 : (gi == 1) ? Wh1 : Wh2;
    const short* Wl = (gi == 0) ? Wl0 : (gi == 1) ? Wl1 : Wl2;
    float* partial  = (gi == 0) ? p0 : (gi == 1) ? p1 : p2;
    const int Trows = (gi == 0) ? 10 : (gi == 1) ? 20 : 256;
    const int toff  = (gi == 0) ? 246 : (gi == 1) ? 236 : 0;
    const int M     = (gi == 0) ? 40 : (gi == 1) ? 80 : 1024;
    const int R0 = mtid * 64;

    const int tid  = threadIdx.x;
    const int lane = tid & 63;
    const int wave = tid >> 6;
    const int wr = (wave & 1) * 32;
    const int wg = (wave >> 1) * 96;
    const int q = lane >> 4, r16 = lane & 15;

    const int sa_r = tid >> 2, sa_kq = tid & 3;
    const bool vldA = (R0 + sa_r < M);
    int btA = 0;
    if (vldA) { int R = R0 + sa_r; int b = R / Trows, t = R - b * Trows; btA = b * 256 + toff + t; }

    f32x4 acc[2][6];
    #pragma unroll
    for (int i = 0; i < 2; ++i)
        #pragma unroll
        for (int j = 0; j < 6; ++j) acc[i][j] = (f32x4){0.f, 0.f, 0.f, 0.f};

    for (int c = 0; c < KSL / 32; ++c) {
        const int k0 = ks * KSL + c * 32;
        {
            const int kk = k0 + sa_kq * 8;
            const int nn = kk >> 6, d0 = kk & 63;
            uint4 u0 = make_uint4(0u, 0u, 0u, 0u), u1 = u0;
            if (vldA) {
                const unsigned int* src = &Xhl[((size_t)nn * BS_TOT + btA) * 64 + d0];
                u0 = *(const uint4*)src;
                u1 = *(const uint4*)(src + 4);
            }
            short4 h0 = make_short4((short)(u0.x & 0xFFFF), (short)(u0.y & 0xFFFF),
                                    (short)(u0.z & 0xFFFF), (short)(u0.w & 0xFFFF));
            short4 l0 = make_short4((short)(u0.x >> 16), (short)(u0.y >> 16),
                                    (short)(u0.z >> 16), (short)(u0.w >> 16));
            short4 h1 = make_short4((short)(u1.x & 0xFFFF), (short)(u1.y & 0xFFFF),
                                    (short)(u1.z & 0xFFFF), (short)(u1.w & 0xFFFF));
            short4 l1 = make_short4((short)(u1.x >> 16), (short)(u1.y >> 16),
                                    (short)(u1.z >> 16), (short)(u1.w >> 16));
            int kb = swz_k(sa_r, sa_kq * 16);
            char* rowH = (char*)Ah + sa_r * 80;
            char* rowL = (char*)Al + sa_r * 80;
            *(short4*)(rowH + kb) = h0; *(short4*)(rowH + kb + 8) = h1;
            *(short4*)(rowL + kb) = l0; *(short4*)(rowL + kb + 8) = l1;
        }
        #pragma unroll
        for (int l = 0; l < 3; ++l) {
            int idx = tid + l * 256;
            int g = idx >> 2, kq = idx & 3;
            const size_t src = (size_t)g * I_DIM + k0 + kq * 8;
            bf16x8 hv = *(const bf16x8*)&Wh[src];
            bf16x8 lv = *(const bf16x8*)&Wl[src];
            int kb = swz_k(g, kq * 16);
            *(bf16x8*)((char*)Bh + g * 80 + kb) = hv;
            *(bf16x8*)((char*)Bl + g * 80 + kb) = lv;
        }
        __syncthreads();
        bf16x8 ah[2], al[2];
        #pragma unroll
        for (int mi = 0; mi < 2; ++mi) {
            int row = wr + mi * 16 + r16;
            int kb = swz_k(row, q * 16);
            ah[mi] = *(const bf16x8*)((const char*)Ah + row * 80 + kb);
            al[mi] = *(const bf16x8*)((const char*)Al + row * 80 + kb);
        }
        #pragma unroll
        for (int ci = 0; ci < 6; ++ci) {
            int grow = wg + ci * 16 + r16;
            int kb = swz_k(grow, q * 16);
            bf16x8 bh = *(const bf16x8*)((const char*)Bh + grow * 80 + kb);
            bf16x8 bl = *(const bf16x8*)((const char*)Bl + grow * 80 + kb);
            #pragma unroll
            for (int mi = 0; mi < 2; ++mi) {
                acc[mi][ci] = __builtin_amdgcn_mfma_f32_16x16x32_bf16(ah[mi], bh, acc[mi][ci], 0, 0, 0);
                acc[mi][ci] = __builtin_amdgcn_mfma_f32_16x16x32_bf16(ah[mi], bl, acc[mi][ci], 0, 0, 0);
                acc[mi][ci] = __builtin_amdgcn_mfma_f32_16x16x32_bf16(al[mi], bh, acc[mi][ci], 0, 0, 0);
            }
        }
        __syncthreads();
    }
    #pragma unroll
    for (int mi = 0; mi < 2; ++mi) {
        #pragma unroll
        for (int r = 0; r < 4; ++r) {
            int R = R0 + wr + mi * 16 + q * 4 + r;
            if (R < M) {
                #pragma unroll
                for (int ci = 0; ci < 6; ++ci)
                    partial[((size_t)ks * M + R) * 192 + wg + ci * 16 + r16] = acc[mi][ci][r];
            }
        }
    }
}

// ---------------------------------------------------------------- reduce (all 3 fused)
__global__ __launch_bounds__(192)
void gru_reduce_fused_kernel(const float* __restrict__ p0, const float* __restrict__ p1,
                             const float* __restrict__ p2,
                             const float* __restrict__ bih0, const float* __restrict__ bih1,
                             const float* __restrict__ bih2,
                             float* __restrict__ xp0, float* __restrict__ xp1,
                             float* __restrict__ xp2)
{
    int r = blockIdx.x;
    const float* partial; const float* bih; float* xp; int M;
    if (r < 40)       { partial = p0; bih = bih0; xp = xp0; M = 40; }
    else if (r < 120) { r -= 40;  partial = p1; bih = bih1; xp = xp1; M = 80; }
    else              { r -= 120; partial = p2; bih = bih2; xp = xp2; M = 1024; }
    const int g = threadIdx.x;
    float acc = bih[g];
    for (int ks = 0; ks < KS_GRU; ++ks)
        acc += partial[((size_t)ks * M + r) * 192 + g];
    xp[(size_t)r * 192 + g] = acc;
}

// ---------------------------------------------------------------- GRU scan
__global__ __launch_bounds__(192)
void gru_scan_kernel(const float* __restrict__ xp_s, const float* __restrict__ xp_m,
                     const float* __restrict__ xp_l,
                     const float* __restrict__ Whh_s, const float* __restrict__ Whh_m,
                     const float* __restrict__ Whh_l,
                     const float* __restrict__ bhh_s, const float* __restrict__ bhh_m,
                     const float* __restrict__ bhh_l,
                     float* __restrict__ hcat)
{
    __shared__ float h[64];
    __shared__ float gh[192];
    const int blk = blockIdx.x;
    const int g3 = blk >> 2, b = blk & 3;
    const float* xp  = (g3 == 0) ? xp_s : (g3 == 1) ? xp_m : xp_l;
    const float* Whh = (g3 == 0) ? Whh_s : (g3 == 1) ? Whh_m : Whh_l;
    const float* bhh = (g3 == 0) ? bhh_s : (g3 == 1) ? bhh_m : bhh_l;
    const int T = (g3 == 0) ? 10 : (g3 == 1) ? 20 : 256;
    const int g = threadIdx.x;

    float w[64];
    #pragma unroll
    for (int k4 = 0; k4 < 16; ++k4) {
        float4 v = *(const float4*)&Whh[g * 64 + k4 * 4];
        w[k4 * 4 + 0] = v.x; w[k4 * 4 + 1] = v.y;
        w[k4 * 4 + 2] = v.z; w[k4 * 4 + 3] = v.w;
    }
    const float bh = bhh[g];
    if (g < 64) h[g] = 0.f;

    const float* xpb = xp + (size_t)b * T * 192;
    float xr_c = 0.f, xz_c = 0.f, xn_c = 0.f;
    if (g < 64) { xr_c = xpb[g]; xz_c = xpb[64 + g]; xn_c = xpb[128 + g]; }
    __syncthreads();

    for (int t = 0; t < T; ++t) {
        float xr_n = 0.f, xz_n = 0.f, xn_n = 0.f;
        if (t + 1 < T && g < 64) {
            const float* xq = xpb + (size_t)(t + 1) * 192;
            xr_n = xq[g]; xz_n = xq[64 + g]; xn_n = xq[128 + g];
        }
        float a0 = 0.f, a1 = 0.f, a2 = 0.f, a3 = 0.f;
        #pragma unroll
        for (int k4 = 0; k4 < 16; ++k4) {
            float4 hv = ((const float4*)h)[k4];
            a0 += hv.x * w[k4 * 4 + 0];
            a1 += hv.y * w[k4 * 4 + 1];
            a2 += hv.z * w[k4 * 4 + 2];
            a3 += hv.w * w[k4 * 4 + 3];
        }
        gh[g] = bh + ((a0 + a1) + (a2 + a3));
        __syncthreads();
        if (g < 64) {
            float hr = gh[g], hz = gh[64 + g], hn = gh[128 + g];
            float r = 1.f / (1.f + __expf(-(xr_c + hr)));
            float z = 1.f / (1.f + __expf(-(xz_c + hz)));
            float pre = xn_c + r * hn;
            float e2 = __expf(2.f * pre);
            float nv = 1.f - 2.f / (e2 + 1.f);   // tanh
            h[g] = (1.f - z) * nv + z * h[g];
        }
        __syncthreads();
        xr_c = xr_n; xz_c = xz_n; xn_c = xn_n;
    }
    if (g < 64) hcat[b * 192 + g3 * 64 + g] = h[g];
}

// ---------------------------------------------------------------- head
__global__ __launch_bounds__(512)
void head_kernel(const float* __restrict__ hcat,
                 const float* __restrict__ W1, const float* __restrict__ b1,
                 const float* __restrict__ W2, const float* __restrict__ b2,
                 float* __restrict__ out)
{
    __shared__ float hc[4][192];
    __shared__ float h1[4][64];
    const int tid = threadIdx.x;
    for (int i = tid; i < 768; i += 512) hc[i / 192][i % 192] = hcat[i];
    __syncthreads();
    if (tid < 256) {
        int b = tid >> 6, e = tid & 63;
        float acc = b1[e];
        #pragma unroll
        for (int k = 0; k < 192; ++k) acc += hc[b][k] * W1[e * 192 + k];
        h1[b][e] = gelu_f(acc);
    }
    __syncthreads();
    for (int o = tid; o < 2000; o += 512) {
        int b = o / 500, n = o % 500;
        float acc = b2[n];
        #pragma unroll
        for (int k = 0; k < 64; ++k) acc += h1[b][k] * W2[n * 64 + k];
        out[o] = acc;
    }
}

// ================================================================ launch
extern "C" void kernel_launch(void* const* d_in, const int* in_sizes, int n_in,
                              void* d_out, int out_size, void* d_ws, size_t ws_size,
                              hipStream_t stream)
{
    (void)in_sizes; (void)n_in; (void)out_size; (void)ws_size;
    const float* x    = (const float*)d_in[0];
    const float* ipW  = (const float*)d_in[1];
    const float* ipb  = (const float*)d_in[2];
    const float* fe   = (const float*)d_in[3];
    const float* te   = (const float*)d_in[4];
    const float* glW  = (const float*)d_in[5];
    const float* glb  = (const float*)d_in[6];
    const float* glg  = (const float*)d_in[7];
    const float* glbe = (const float*)d_in[8];
    const float* Wih[3] = {(const float*)d_in[9],  (const float*)d_in[13], (const float*)d_in[17]};
    const float* Whh[3] = {(const float*)d_in[10], (const float*)d_in[14], (const float*)d_in[18]};
    const float* bih[3] = {(const float*)d_in[11], (const float*)d_in[15], (const float*)d_in[19]};
    const float* bhh[3] = {(const float*)d_in[12], (const float*)d_in[16], (const float*)d_in[20]};
    const float* W1 = (const float*)d_in[21];
    const float* b1 = (const float*)d_in[22];
    const float* W2 = (const float*)d_in[23];
    const float* b2 = (const float*)d_in[24];
    float* out = (float*)d_out;

    unsigned int* Xhl = (unsigned int*)d_ws;          // 32,768,000 uints (131 MB)
    unsigned int* Yhl = Xhl + 32768000;               // 32,768,000 uints (131 MB)
    short* adjTh = (short*)(Yhl + 32768000);          // 512*512 shorts
    short* adjTl = adjTh + NPAD * NPAD;
    short* glWh  = adjTl + NPAD * NPAD;               // 8192 shorts (2 layers)
    short* glWl  = glWh + 8192;
    short* ipWh  = glWl + 8192;                       // 2048 shorts
    short* ipWl  = ipWh + 2048;
    // GRU-phase scratch overlays Yhl (dead after layer-2):
    short* wbase = (short*)Yhl;
    short* Wh0 = wbase;                               // 6,144,000 shorts each
    short* Wl0 = Wh0 + 6144000;
    short* Wh1 = Wl0 + 6144000;
    short* Wl1 = Wh1 + 6144000;
    short* Wh2 = Wl1 + 6144000;
    short* Wl2 = Wh2 + 6144000;
    float* pbase = (float*)Yhl + 18432000;
    float* part0 = pbase;                             // 40*40*192   = 307,200
    float* part1 = part0 + 307200;                    // 40*80*192   = 614,400
    float* part2 = part1 + 614400;                    // 40*1024*192 = 7,864,320
    float* xp0   = part2 + 7864320;                   // 7,680
    float* xp1   = xp0 + 7680;                        // 15,360
    float* xp2   = xp1 + 15360;                       // 196,608
    float* hcat  = xp2 + 196608;                      // 768

    hipMemsetAsync(adjTh, 0, (size_t)NPAD * NPAD * 2 * sizeof(short), stream);
    adj_kernel<<<NN, 512, 0, stream>>>(fe, te, adjTh, adjTl);
    wsplit_kernel<<<8, 256, 0, stream>>>(glW, glWh, glWl, 2048);
    wsplit_kernel<<<2, 256, 0, stream>>>(ipW, ipWh, ipWl, 512);
    proj_mfma_kernel<<<4000, 256, 0, stream>>>(x, ipWh, ipWl, ipb, Xhl);

    // layer 1: Xhl -> Yhl (agg+residual), then h+LN in-place on Yhl
    agg_mfma_kernel<<<dim3(512, 4), 256, 0, stream>>>(Xhl, adjTh, adjTl, Yhl);
    hln_stream_kernel<<<4000, 256, 0, stream>>>(Yhl, glWh, glWl, glb, glg, glbe);
    // layer 2: Yhl -> Xhl, then in-place on Xhl
    agg_mfma_kernel<<<dim3(512, 4), 256, 0, stream>>>(Yhl, adjTh, adjTl, Xhl);
    hln_stream_kernel<<<4000, 256, 0, stream>>>(Xhl, glWh + 4096, glWl + 4096,
                                                glb + 64, glg + 64, glbe + 64);

    wconv_kernel<<<dim3(6000, 3), 256, 0, stream>>>(Wih[0], Wih[1], Wih[2],
                                                    Wh0, Wl0, Wh1, Wl1, Wh2, Wl2);
    gru_pre_mfma_kernel<<<760, 256, 0, stream>>>(Xhl, Wh0, Wl0, Wh1, Wl1, Wh2, Wl2,
                                                 part0, part1, part2);
    gru_reduce_fused_kernel<<<1144, 192, 0, stream>>>(part0, part1, part2,
                                                      bih[0], bih[1], bih[2],
                                                      xp0, xp1, xp2);
    gru_scan_kernel<<<12, 192, 0, stream>>>(xp0, xp1, xp2,
                                            Whh[0], Whh[1], Whh[2],
                                            bhh[0], bhh[1], bhh[2], hcat);
    head_kernel<<<1, 512, 0, stream>>>(hcat, W1, b1, W2, b2, out);
}

// Round 16
// 760.257 us; speedup vs baseline: 1.1709x; 1.0419x over previous
//
#include <hip/hip_runtime.h>
#include <math.h>

#define NN 500
#define DD 64
#define NPAD 512             // adjT padded to [512][512]
#define COLS 65536           // 1024 * 64
#define BS_TOT 1024          // B*S
#define I_DIM 32000          // N*D
#define KS_GRU 40            // K-split for GRU pre-GEMM
#define KSL 800              // 32000/40

typedef __attribute__((ext_vector_type(8))) short bf16x8;
typedef __attribute__((ext_vector_type(4))) float f32x4;

__device__ __forceinline__ float gelu_f(float x) {
    return 0.5f * x * (1.0f + erff(x * 0.70710678118654752440f));
}

__device__ __forceinline__ unsigned short bf16_rn(float x) {
    unsigned int u = __float_as_uint(x);
    unsigned int r = u + 0x7FFFu + ((u >> 16) & 1u);
    return (unsigned short)(r >> 16);
}
__device__ __forceinline__ float bf16_tof(unsigned short h) {
    return __uint_as_float(((unsigned int)h) << 16);
}
// packed split-bf16: u = hi | (lo<<16); value = tof(hi)+tof(lo)
__device__ __forceinline__ unsigned int pack_hl(float x) {
    unsigned short h = bf16_rn(x);
    unsigned short l = bf16_rn(x - bf16_tof(h));
    return (unsigned int)h | ((unsigned int)l << 16);
}
__device__ __forceinline__ float unpack_val(unsigned int u) {
    return __uint_as_float(u << 16) + __uint_as_float(u & 0xFFFF0000u);
}
__device__ __forceinline__ void split4(float4 v, short4& h4, short4& l4) {
    h4.x = (short)bf16_rn(v.x); l4.x = (short)bf16_rn(v.x - bf16_tof((unsigned short)h4.x));
    h4.y = (short)bf16_rn(v.y); l4.y = (short)bf16_rn(v.y - bf16_tof((unsigned short)h4.y));
    h4.z = (short)bf16_rn(v.z); l4.z = (short)bf16_rn(v.z - bf16_tof((unsigned short)h4.z));
    h4.w = (short)bf16_rn(v.w); l4.w = (short)bf16_rn(v.w - bf16_tof((unsigned short)h4.w));
}

// LDS XOR swizzle (16B granularity within 64B k-extent) — used by gru_pre
__device__ __forceinline__ int swz_k(int row, int kbyte) {
    return kbyte ^ (((row >> 3) & 3) << 4);
}

// fragment-major LDS byte offset: fragment (row>>4, q) holds 16 lanes x 16B
__device__ __forceinline__ int frag_off(int row, int q) {
    return ((((row >> 4) * 4 + q) * 16) + (row & 15)) * 16;
}

// ---------------------------------------------------------------- adjacency
__global__ __launch_bounds__(512)
void adj_kernel(const float* __restrict__ fe, const float* __restrict__ te,
                short* __restrict__ adjTh, short* __restrict__ adjTl)
{
    __shared__ float fr[32];
    __shared__ float red[8];
    __shared__ float red2[8];
    const int n = blockIdx.x;
    const int tid = threadIdx.x;
    if (tid < 32) fr[tid] = fe[n * 32 + tid];
    __syncthreads();
    const int m = tid;
    float s = -1e30f;
    if (m < NN) {
        float acc = 0.f;
        #pragma unroll
        for (int f = 0; f < 32; ++f) acc += fr[f] * te[m * 32 + f];
        s = acc * 2.0f;   // 1/TEMP
    }
    float v = s;
    #pragma unroll
    for (int off = 32; off; off >>= 1) v = fmaxf(v, __shfl_xor(v, off));
    if ((tid & 63) == 0) red[tid >> 6] = v;
    __syncthreads();
    float bmax = red[0];
    #pragma unroll
    for (int i = 1; i < 8; ++i) bmax = fmaxf(bmax, red[i]);
    float e = (m < NN) ? expf(s - bmax) : 0.f;
    float v2 = e;
    #pragma unroll
    for (int off = 32; off; off >>= 1) v2 += __shfl_xor(v2, off);
    if ((tid & 63) == 0) red2[tid >> 6] = v2;
    __syncthreads();
    float bsum = 0.f;
    #pragma unroll
    for (int i = 0; i < 8; ++i) bsum += red2[i];
    if (m < NN) {
        float p = e / bsum;
        unsigned short h = bf16_rn(p);
        adjTh[(size_t)m * NPAD + n] = (short)h;
        adjTl[(size_t)m * NPAD + n] = (short)bf16_rn(p - bf16_tof(h));
    }
}

// ---------------------------------------------------------------- generic split-convert
__global__ __launch_bounds__(256)
void wsplit_kernel(const float* __restrict__ W, short* __restrict__ H,
                   short* __restrict__ L, int n4)
{
    int i = blockIdx.x * 256 + threadIdx.x;
    if (i < n4) {
        float4 v = *(const float4*)&W[i * 4];
        short4 h4, l4;
        split4(v, h4, l4);
        *(short4*)&H[i * 4] = h4;
        *(short4*)&L[i * 4] = l4;
    }
}

// ---------------------------------------------------------------- input proj (streaming MFMA, no LDS)
__global__ __launch_bounds__(256)
void proj_mfma_kernel(const float* __restrict__ xin,
                      const short* __restrict__ Wh, const short* __restrict__ Wl,
                      const float* __restrict__ ipb, unsigned int* __restrict__ Xhl)
{
    const int tid  = threadIdx.x;
    const int lane = tid & 63;
    const int wave = tid >> 6;
    const int q = lane >> 4, r16 = lane & 15;
    const size_t row0 = (size_t)blockIdx.x * 128 + wave * 32;

    float bB[4];
    #pragma unroll
    for (int ci = 0; ci < 4; ++ci) bB[ci] = ipb[ci * 16 + r16];

    bf16x8 wh[4], wl[4];
    #pragma unroll
    for (int ci = 0; ci < 4; ++ci) {
        int off = (ci * 16 + r16) * 32 + q * 8;
        wh[ci] = *(const bf16x8*)&Wh[off];
        wl[ci] = *(const bf16x8*)&Wl[off];
    }

    f32x4 acc[2][4];
    #pragma unroll
    for (int i = 0; i < 2; ++i)
        #pragma unroll
        for (int j = 0; j < 4; ++j) acc[i][j] = (f32x4){0.f, 0.f, 0.f, 0.f};

    #pragma unroll
    for (int mi = 0; mi < 2; ++mi) {
        const size_t row = row0 + mi * 16 + r16;
        const int n = (int)(row >> 10), bs = (int)(row & 1023);
        const float* src = &xin[((size_t)bs * NN + n) * 32 + q * 8];
        float4 v0 = *(const float4*)src;
        float4 v1 = *(const float4*)(src + 4);
        short4 h0, l0, h1, l1;
        split4(v0, h0, l0);
        split4(v1, h1, l1);
        bf16x8 ah, al;
        ah[0] = h0.x; ah[1] = h0.y; ah[2] = h0.z; ah[3] = h0.w;
        ah[4] = h1.x; ah[5] = h1.y; ah[6] = h1.z; ah[7] = h1.w;
        al[0] = l0.x; al[1] = l0.y; al[2] = l0.z; al[3] = l0.w;
        al[4] = l1.x; al[5] = l1.y; al[6] = l1.z; al[7] = l1.w;
        #pragma unroll
        for (int ci = 0; ci < 4; ++ci) {
            acc[mi][ci] = __builtin_amdgcn_mfma_f32_16x16x32_bf16(ah, wh[ci], acc[mi][ci], 0, 0, 0);
            acc[mi][ci] = __builtin_amdgcn_mfma_f32_16x16x32_bf16(ah, wl[ci], acc[mi][ci], 0, 0, 0);
            acc[mi][ci] = __builtin_amdgcn_mfma_f32_16x16x32_bf16(al, wh[ci], acc[mi][ci], 0, 0, 0);
        }
    }

    #pragma unroll
    for (int mi = 0; mi < 2; ++mi) {
        #pragma unroll
        for (int rg = 0; rg < 4; ++rg) {
            size_t grow = row0 + mi * 16 + q * 4 + rg;
            #pragma unroll
            for (int ci = 0; ci < 4; ++ci) {
                float y = gelu_f(acc[mi][ci][rg] + bB[ci]);
                Xhl[grow * 64 + ci * 16 + r16] = pack_hl(y);
            }
        }
    }
}

// ---------------------------------------------------------------- agg GEMM (split-bf16 MFMA, dbuf, fragment-major LDS)
// C[m][c] = sum_n adjT[m][n]*X[n][c] + X[m][c]; packed in/out.
// LDS tiles stored fragment-major: (row>>4, q) fragment = 16 lanes x 16B
// contiguous -> conflict-free ds_read_b128 and staging writes. 64 KB total.
__global__ __launch_bounds__(256)
void agg_mfma_kernel(const unsigned int* __restrict__ Xhl,
                     const short* __restrict__ adjTh, const short* __restrict__ adjTl,
                     unsigned int* __restrict__ Yhl)
{
    __shared__ __align__(16) short Ah[2][4096];
    __shared__ __align__(16) short Al[2][4096];
    __shared__ __align__(16) short Bh[2][4096];
    __shared__ __align__(16) short Bl[2][4096];

    const int tid  = threadIdx.x;
    const int lane = tid & 63;
    const int wave = tid >> 6;
    const int wm = (wave >> 1) * 64;
    const int wc = (wave & 1) * 64;
    const int q = lane >> 4, r16 = lane & 15;
    const int c0 = blockIdx.x * 128;
    const int m0 = blockIdx.y * 128;

    const int sa_m = tid >> 1, sa_kh = tid & 1;
    const int sb_c = tid & 127, sb_kh = tid >> 7;
    const size_t cb = (size_t)(c0 + sb_c);

    f32x4 acc[4][4];
    #pragma unroll
    for (int i = 0; i < 4; ++i)
        #pragma unroll
        for (int j = 0; j < 4; ++j) acc[i][j] = (f32x4){0.f, 0.f, 0.f, 0.f};

    // ---- prologue: stage chunk 0 into buffer 0
    {
        const size_t base = (size_t)(m0 + sa_m) * NPAD + sa_kh * 16;
        bf16x8 h0 = *(const bf16x8*)&adjTh[base];
        bf16x8 h1 = *(const bf16x8*)&adjTh[base + 8];
        bf16x8 l0 = *(const bf16x8*)&adjTl[base];
        bf16x8 l1 = *(const bf16x8*)&adjTl[base + 8];
        *(bf16x8*)((char*)Ah[0] + frag_off(sa_m, sa_kh * 2))     = h0;
        *(bf16x8*)((char*)Ah[0] + frag_off(sa_m, sa_kh * 2 + 1)) = h1;
        *(bf16x8*)((char*)Al[0] + frag_off(sa_m, sa_kh * 2))     = l0;
        *(bf16x8*)((char*)Al[0] + frag_off(sa_m, sa_kh * 2 + 1)) = l1;

        unsigned int u[16];
        #pragma unroll
        for (int j = 0; j < 16; ++j) {
            int kk = sb_kh * 16 + j;
            u[j] = (kk < NN) ? Xhl[(size_t)kk * COLS + cb] : 0u;
        }
        bf16x8 bh0, bh1, bl0, bl1;
        #pragma unroll
        for (int j = 0; j < 8; ++j) {
            bh0[j] = (short)(u[j] & 0xFFFFu);     bl0[j] = (short)(u[j] >> 16);
            bh1[j] = (short)(u[8 + j] & 0xFFFFu); bl1[j] = (short)(u[8 + j] >> 16);
        }
        *(bf16x8*)((char*)Bh[0] + frag_off(sb_c, sb_kh * 2))     = bh0;
        *(bf16x8*)((char*)Bh[0] + frag_off(sb_c, sb_kh * 2 + 1)) = bh1;
        *(bf16x8*)((char*)Bl[0] + frag_off(sb_c, sb_kh * 2))     = bl0;
        *(bf16x8*)((char*)Bl[0] + frag_off(sb_c, sb_kh * 2 + 1)) = bl1;
    }
    __syncthreads();

    for (int kc = 0; kc < 16; ++kc) {
        const int cur = kc & 1;
        // ---- (1) issue next-chunk global loads into registers
        bf16x8 nAh0, nAh1, nAl0, nAl1;
        unsigned int nu[16];
        if (kc < 15) {
            const int k0n = (kc + 1) * 32;
            const size_t base = (size_t)(m0 + sa_m) * NPAD + k0n + sa_kh * 16;
            nAh0 = *(const bf16x8*)&adjTh[base];
            nAh1 = *(const bf16x8*)&adjTh[base + 8];
            nAl0 = *(const bf16x8*)&adjTl[base];
            nAl1 = *(const bf16x8*)&adjTl[base + 8];
            #pragma unroll
            for (int j = 0; j < 16; ++j) {
                int kk = k0n + sb_kh * 16 + j;
                nu[j] = (kk < NN) ? Xhl[(size_t)kk * COLS + cb] : 0u;
            }
        }
        // ---- (2) compute current chunk from LDS buf cur (conflict-free frag reads)
        bf16x8 ah[4], al[4];
        #pragma unroll
        for (int mi = 0; mi < 4; ++mi) {
            int off = frag_off(wm + mi * 16 + r16, q);
            ah[mi] = *(const bf16x8*)((const char*)Ah[cur] + off);
            al[mi] = *(const bf16x8*)((const char*)Al[cur] + off);
        }
        #pragma unroll
        for (int ci = 0; ci < 4; ++ci) {
            int off = frag_off(wc + ci * 16 + r16, q);
            bf16x8 bh = *(const bf16x8*)((const char*)Bh[cur] + off);
            bf16x8 bl = *(const bf16x8*)((const char*)Bl[cur] + off);
            #pragma unroll
            for (int mi = 0; mi < 4; ++mi) {
                acc[mi][ci] = __builtin_amdgcn_mfma_f32_16x16x32_bf16(ah[mi], bh, acc[mi][ci], 0, 0, 0);
                acc[mi][ci] = __builtin_amdgcn_mfma_f32_16x16x32_bf16(ah[mi], bl, acc[mi][ci], 0, 0, 0);
                acc[mi][ci] = __builtin_amdgcn_mfma_f32_16x16x32_bf16(al[mi], bh, acc[mi][ci], 0, 0, 0);
            }
        }
        // ---- (3) write next chunk into buf cur^1
        if (kc < 15) {
            const int nb = cur ^ 1;
            *(bf16x8*)((char*)Ah[nb] + frag_off(sa_m, sa_kh * 2))     = nAh0;
            *(bf16x8*)((char*)Ah[nb] + frag_off(sa_m, sa_kh * 2 + 1)) = nAh1;
            *(bf16x8*)((char*)Al[nb] + frag_off(sa_m, sa_kh * 2))     = nAl0;
            *(bf16x8*)((char*)Al[nb] + frag_off(sa_m, sa_kh * 2 + 1)) = nAl1;
            bf16x8 bh0, bh1, bl0, bl1;
            #pragma unroll
            for (int j = 0; j < 8; ++j) {
                bh0[j] = (short)(nu[j] & 0xFFFFu);     bl0[j] = (short)(nu[j] >> 16);
                bh1[j] = (short)(nu[8 + j] & 0xFFFFu); bl1[j] = (short)(nu[8 + j] >> 16);
            }
            *(bf16x8*)((char*)Bh[nb] + frag_off(sb_c, sb_kh * 2))     = bh0;
            *(bf16x8*)((char*)Bh[nb] + frag_off(sb_c, sb_kh * 2 + 1)) = bh1;
            *(bf16x8*)((char*)Bl[nb] + frag_off(sb_c, sb_kh * 2))     = bl0;
            *(bf16x8*)((char*)Bl[nb] + frag_off(sb_c, sb_kh * 2 + 1)) = bl1;
        }
        // ---- (4) single barrier per chunk
        __syncthreads();
    }

    // ---- epilogue: residual + store packed
    #pragma unroll
    for (int mi = 0; mi < 4; ++mi) {
        #pragma unroll
        for (int r = 0; r < 4; ++r) {
            int m = m0 + wm + mi * 16 + q * 4 + r;
            if (m < NN) {
                #pragma unroll
                for (int ci = 0; ci < 4; ++ci) {
                    size_t idx = (size_t)m * COLS + c0 + wc + ci * 16 + r16;
                    float y = acc[mi][ci][r] + unpack_val(Xhl[idx]);
                    Yhl[idx] = pack_hl(y);
                }
            }
        }
    }
}

// ---------------------------------------------------------------- h + LN, streaming MFMA (no LDS, no barriers, in-place)
__global__ __launch_bounds__(256)
void hln_stream_kernel(unsigned int* __restrict__ Xio,
                       const short* __restrict__ Wh, const short* __restrict__ Wl,
                       const float* __restrict__ glb, const float* __restrict__ glg,
                       const float* __restrict__ glbe)
{
    const int tid  = threadIdx.x;
    const int lane = tid & 63;
    const int wave = tid >> 6;
    const int q = lane >> 4, r16 = lane & 15;
    const size_t row0 = (size_t)blockIdx.x * 128 + wave * 32;

    float bB2[4], bG2[4], bE2[4];
    #pragma unroll
    for (int ci = 0; ci < 4; ++ci) {
        int e = ci * 16 + r16;
        bB2[ci] = glb[e]; bG2[ci] = glg[e]; bE2[ci] = glbe[e];
    }

    f32x4 acc[2][4];
    #pragma unroll
    for (int i = 0; i < 2; ++i)
        #pragma unroll
        for (int j = 0; j < 4; ++j) acc[i][j] = (f32x4){0.f, 0.f, 0.f, 0.f};

    #pragma unroll
    for (int kh = 0; kh < 2; ++kh) {
        bf16x8 wh[4], wl[4];
        #pragma unroll
        for (int ci = 0; ci < 4; ++ci) {
            int off = (ci * 16 + r16) * 64 + kh * 32 + q * 8;
            wh[ci] = *(const bf16x8*)&Wh[off];
            wl[ci] = *(const bf16x8*)&Wl[off];
        }
        #pragma unroll
        for (int mi = 0; mi < 2; ++mi) {
            const size_t row = row0 + mi * 16 + r16;
            const unsigned int* src = &Xio[row * 64 + kh * 32 + q * 8];
            uint4 u0 = *(const uint4*)src;
            uint4 u1 = *(const uint4*)(src + 4);
            bf16x8 ah, al;
            ah[0] = (short)(u0.x & 0xFFFFu); al[0] = (short)(u0.x >> 16);
            ah[1] = (short)(u0.y & 0xFFFFu); al[1] = (short)(u0.y >> 16);
            ah[2] = (short)(u0.z & 0xFFFFu); al[2] = (short)(u0.z >> 16);
            ah[3] = (short)(u0.w & 0xFFFFu); al[3] = (short)(u0.w >> 16);
            ah[4] = (short)(u1.x & 0xFFFFu); al[4] = (short)(u1.x >> 16);
            ah[5] = (short)(u1.y & 0xFFFFu); al[5] = (short)(u1.y >> 16);
            ah[6] = (short)(u1.z & 0xFFFFu); al[6] = (short)(u1.z >> 16);
            ah[7] = (short)(u1.w & 0xFFFFu); al[7] = (short)(u1.w >> 16);
            #pragma unroll
            for (int ci = 0; ci < 4; ++ci) {
                acc[mi][ci] = __builtin_amdgcn_mfma_f32_16x16x32_bf16(ah, wh[ci], acc[mi][ci], 0, 0, 0);
                acc[mi][ci] = __builtin_amdgcn_mfma_f32_16x16x32_bf16(ah, wl[ci], acc[mi][ci], 0, 0, 0);
                acc[mi][ci] = __builtin_amdgcn_mfma_f32_16x16x32_bf16(al, wh[ci], acc[mi][ci], 0, 0, 0);
            }
        }
    }

    #pragma unroll
    for (int mi = 0; mi < 2; ++mi) {
        #pragma unroll
        for (int rg = 0; rg < 4; ++rg) {
            float h[4];
            float s1 = 0.f;
            #pragma unroll
            for (int ci = 0; ci < 4; ++ci) {
                h[ci] = gelu_f(acc[mi][ci][rg] + bB2[ci]);
                s1 += h[ci];
            }
            #pragma unroll
            for (int off = 1; off < 16; off <<= 1) s1 += __shfl_xor(s1, off);
            float mu = s1 * (1.f / 64.f);
            float s2 = 0.f;
            #pragma unroll
            for (int ci = 0; ci < 4; ++ci) { float dc = h[ci] - mu; s2 += dc * dc; }
            #pragma unroll
            for (int off = 1; off < 16; off <<= 1) s2 += __shfl_xor(s2, off);
            float rs = 1.f / sqrtf(s2 * (1.f / 64.f) + 1e-5f);
            size_t grow = row0 + mi * 16 + q * 4 + rg;
            #pragma unroll
            for (int ci = 0; ci < 4; ++ci) {
                float y = (h[ci] - mu) * rs * bG2[ci] + bE2[ci];
                Xio[grow * 64 + ci * 16 + r16] = pack_hl(y);
            }
        }
    }
}

// ---------------------------------------------------------------- Wih split-convert
__global__ __launch_bounds__(256)
void wconv_kernel(const float* __restrict__ W0, const float* __restrict__ W1,
                  const float* __restrict__ W2,
                  short* __restrict__ h0, short* __restrict__ l0,
                  short* __restrict__ h1, short* __restrict__ l1,
                  short* __restrict__ h2, short* __restrict__ l2)
{
    const int gi = blockIdx.y;
    const float* W = (gi == 0) ? W0 : (gi == 1) ? W1 : W2;
    short* H = (gi == 0) ? h0 : (gi == 1) ? h1 : h2;
    short* L = (gi == 0) ? l0 : (gi == 1) ? l1 : l2;
    const size_t i = ((size_t)blockIdx.x * 256 + threadIdx.x) * 4;
    float4 v = *(const float4*)&W[i];
    short4 h4, l4;
    split4(v, h4, l4);
    *(short4*)&H[i] = h4;
    *(short4*)&L[i] = l4;
}

// ---------------------------------------------------------------- GRU pre-GEMM (MFMA)
// blocks: [0,40)=s ks; [40,120)=m; [120,760)=l.  ks-major within each GRU so
// blocks sharing a W k-slice are 40 apart (40%8==0 -> same XCD -> L2-hot W).
__global__ __launch_bounds__(256)
void gru_pre_mfma_kernel(const unsigned int* __restrict__ Xhl,
                         const short* __restrict__ Wh0, const short* __restrict__ Wl0,
                         const short* __restrict__ Wh1, const short* __restrict__ Wl1,
                         const short* __restrict__ Wh2, const short* __restrict__ Wl2,
                         float* __restrict__ p0, float* __restrict__ p1,
                         float* __restrict__ p2)
{
    __shared__ __align__(16) short Ah[64 * 40];
    __shared__ __align__(16) short Al[64 * 40];
    __shared__ __align__(16) short Bh[192 * 40];
    __shared__ __align__(16) short Bl[192 * 40];

    const int bid = blockIdx.x;
    int gi, mtid, ks;
    if (bid < 40)       { gi = 0; mtid = 0;             ks = bid; }
    else if (bid < 120) { int r = bid - 40;  gi = 1; ks = r % 40; mtid = r / 40; }
    else                { int r = bid - 120; gi = 2; ks = r % 40; mtid = r / 40; }
    const short* Wh = (gi == 0) ? Wh0 : (gi == 1) ? Wh1 : Wh2;
    const short* Wl = (gi == 0) ? Wl0 : (gi == 1) ? Wl1 : Wl2;
    float* partial  = (gi == 0) ? p0 : (gi == 1) ? p1 : p2;
    const int Trows = (gi == 0) ? 10 : (gi == 1) ? 20 : 256;
    const int toff  = (gi == 0) ? 246 : (gi == 1) ? 236 : 0;
    const int M     = (gi == 0) ? 40 : (gi == 1) ? 80 : 1024;
    const int R0 = mtid * 64;

    const int tid  = threadIdx.x;
    const int lane = tid & 63;
    const int wave = tid >> 6;
    const int wr = (wave & 1) * 32;
    const int wg = (wave >> 1) * 96;
    const int q = lane >> 4, r16 = lane & 15;

    const int sa_r = tid >> 2, sa_kq = tid & 3;
    const bool vldA = (R0 + sa_r < M);
    int btA = 0;
    if (vldA) { int R = R0 + sa_r; int b = R / Trows, t = R - b * Trows; btA = b * 256 + toff + t; }

    f32x4 acc[2][6];
    #pragma unroll
    for (int i = 0; i < 2; ++i)
        #pragma unroll
        for (int j = 0; j < 6; ++j) acc[i][j] = (f32x4){0.f, 0.f, 0.f, 0.f};

    for (int c = 0; c < KSL / 32; ++c) {
        const int k0 = ks * KSL + c * 32;
        {
            const int kk = k0 + sa_kq * 8;
            const int nn = kk >> 6, d0 = kk & 63;
            uint4 u0 = make_uint4(0u, 0u, 0u, 0u), u1 = u0;
            if (vldA) {
                const unsigned int* src = &Xhl[((size_t)nn * BS_TOT + btA) * 64 + d0];
                u0 = *(const uint4*)src;
                u1 = *(const uint4*)(src + 4);
            }
            short4 h0 = make_short4((short)(u0.x & 0xFFFF), (short)(u0.y & 0xFFFF),
                                    (short)(u0.z & 0xFFFF), (short)(u0.w & 0xFFFF));
            short4 l0 = make_short4((short)(u0.x >> 16), (short)(u0.y >> 16),
                                    (short)(u0.z >> 16), (short)(u0.w >> 16));
            short4 h1 = make_short4((short)(u1.x & 0xFFFF), (short)(u1.y & 0xFFFF),
                                    (short)(u1.z & 0xFFFF), (short)(u1.w & 0xFFFF));
            short4 l1 = make_short4((short)(u1.x >> 16), (short)(u1.y >> 16),
                                    (short)(u1.z >> 16), (short)(u1.w >> 16));
            int kb = swz_k(sa_r, sa_kq * 16);
            char* rowH = (char*)Ah + sa_r * 80;
            char* rowL = (char*)Al + sa_r * 80;
            *(short4*)(rowH + kb) = h0; *(short4*)(rowH + kb + 8) = h1;
            *(short4*)(rowL + kb) = l0; *(short4*)(rowL + kb + 8) = l1;
        }
        #pragma unroll
        for (int l = 0; l < 3; ++l) {
            int idx = tid + l * 256;
            int g = idx >> 2, kq = idx & 3;
            const size_t src = (size_t)g * I_DIM + k0 + kq * 8;
            bf16x8 hv = *(const bf16x8*)&Wh[src];
            bf16x8 lv = *(const bf16x8*)&Wl[src];
            int kb = swz_k(g, kq * 16);
            *(bf16x8*)((char*)Bh + g * 80 + kb) = hv;
            *(bf16x8*)((char*)Bl + g * 80 + kb) = lv;
        }
        __syncthreads();
        bf16x8 ah[2], al[2];
        #pragma unroll
        for (int mi = 0; mi < 2; ++mi) {
            int row = wr + mi * 16 + r16;
            int kb = swz_k(row, q * 16);
            ah[mi] = *(const bf16x8*)((const char*)Ah + row * 80 + kb);
            al[mi] = *(const bf16x8*)((const char*)Al + row * 80 + kb);
        }
        #pragma unroll
        for (int ci = 0; ci < 6; ++ci) {
            int grow = wg + ci * 16 + r16;
            int kb = swz_k(grow, q * 16);
            bf16x8 bh = *(const bf16x8*)((const char*)Bh + grow * 80 + kb);
            bf16x8 bl = *(const bf16x8*)((const char*)Bl + grow * 80 + kb);
            #pragma unroll
            for (int mi = 0; mi < 2; ++mi) {
                acc[mi][ci] = __builtin_amdgcn_mfma_f32_16x16x32_bf16(ah[mi], bh, acc[mi][ci], 0, 0, 0);
                acc[mi][ci] = __builtin_amdgcn_mfma_f32_16x16x32_bf16(ah[mi], bl, acc[mi][ci], 0, 0, 0);
                acc[mi][ci] = __builtin_amdgcn_mfma_f32_16x16x32_bf16(al[mi], bh, acc[mi][ci], 0, 0, 0);
            }
        }
        __syncthreads();
    }
    #pragma unroll
    for (int mi = 0; mi < 2; ++mi) {
        #pragma unroll
        for (int r = 0; r < 4; ++r) {
            int R = R0 + wr + mi * 16 + q * 4 + r;
            if (R < M) {
                #pragma unroll
                for (int ci = 0; ci < 6; ++ci)
                    partial[((size_t)ks * M + R) * 192 + wg + ci * 16 + r16] = acc[mi][ci][r];
            }
        }
    }
}

// ---------------------------------------------------------------- reduce (all 3 fused)
__global__ __launch_bounds__(192)
void gru_reduce_fused_kernel(const float* __restrict__ p0, const float* __restrict__ p1,
                             const float* __restrict__ p2,
                             const float* __restrict__ bih0, const float* __restrict__ bih1,
                             const float* __restrict__ bih2,
                             float* __restrict__ xp0, float* __restrict__ xp1,
                             float* __restrict__ xp2)
{
    int r = blockIdx.x;
    const float* partial; const float* bih; float* xp; int M;
    if (r < 40)       { partial = p0; bih = bih0; xp = xp0; M = 40; }
    else if (r < 120) { r -= 40;  partial = p1; bih = bih1; xp = xp1; M = 80; }
    else              { r -= 120; partial = p2; bih = bih2; xp = xp2; M = 1024; }
    const int g = threadIdx.x;
    float acc = bih[g];
    for (int ks = 0; ks < KS_GRU; ++ks)
        acc += partial[((size_t)ks * M + r) * 192 + g];
    xp[(size_t)r * 192 + g] = acc;
}

// ---------------------------------------------------------------- GRU scan
__global__ __launch_bounds__(192)
void gru_scan_kernel(const float* __restrict__ xp_s, const float* __restrict__ xp_m,
                     const float* __restrict__ xp_l,
                     const float* __restrict__ Whh_s, const float* __restrict__ Whh_m,
                     const float* __restrict__ Whh_l,
                     const float* __restrict__ bhh_s, const float* __restrict__ bhh_m,
                     const float* __restrict__ bhh_l,
                     float* __restrict__ hcat)
{
    __shared__ float h[64];
    __shared__ float gh[192];
    const int blk = blockIdx.x;
    const int g3 = blk >> 2, b = blk & 3;
    const float* xp  = (g3 == 0) ? xp_s : (g3 == 1) ? xp_m : xp_l;
    const float* Whh = (g3 == 0) ? Whh_s : (g3 == 1) ? Whh_m : Whh_l;
    const float* bhh = (g3 == 0) ? bhh_s : (g3 == 1) ? bhh_m : bhh_l;
    const int T = (g3 == 0) ? 10 : (g3 == 1) ? 20 : 256;
    const int g = threadIdx.x;

    float w[64];
    #pragma unroll
    for (int k4 = 0; k4 < 16; ++k4) {
        float4 v = *(const float4*)&Whh[g * 64 + k4 * 4];
        w[k4 * 4 + 0] = v.x; w[k4 * 4 + 1] = v.y;
        w[k4 * 4 + 2] = v.z; w[k4 * 4 + 3] = v.w;
    }
    const float bh = bhh[g];
    if (g < 64) h[g] = 0.f;

    const float* xpb = xp + (size_t)b * T * 192;
    float xr_c = 0.f, xz_c = 0.f, xn_c = 0.f;
    if (g < 64) { xr_c = xpb[g]; xz_c = xpb[64 + g]; xn_c = xpb[128 + g]; }
    __syncthreads();

    for (int t = 0; t < T; ++t) {
        float xr_n = 0.f, xz_n = 0.f, xn_n = 0.f;
        if (t + 1 < T && g < 64) {
            const float* xq = xpb + (size_t)(t + 1) * 192;
            xr_n = xq[g]; xz_n = xq[64 + g]; xn_n = xq[128 + g];
        }
        float a0 = 0.f, a1 = 0.f, a2 = 0.f, a3 = 0.f;
        #pragma unroll
        for (int k4 = 0; k4 < 16; ++k4) {
            float4 hv = ((const float4*)h)[k4];
            a0 += hv.x * w[k4 * 4 + 0];
            a1 += hv.y * w[k4 * 4 + 1];
            a2 += hv.z * w[k4 * 4 + 2];
            a3 += hv.w * w[k4 * 4 + 3];
        }
        gh[g] = bh + ((a0 + a1) + (a2 + a3));
        __syncthreads();
        if (g < 64) {
            float hr = gh[g], hz = gh[64 + g], hn = gh[128 + g];
            float r = 1.f / (1.f + __expf(-(xr_c + hr)));
            float z = 1.f / (1.f + __expf(-(xz_c + hz)));
            float pre = xn_c + r * hn;
            float e2 = __expf(2.f * pre);
            float nv = 1.f - 2.f / (e2 + 1.f);   // tanh
            h[g] = (1.f - z) * nv + z * h[g];
        }
        __syncthreads();
        xr_c = xr_n; xz_c = xz_n; xn_c = xn_n;
    }
    if (g < 64) hcat[b * 192 + g3 * 64 + g] = h[g];
}

// ---------------------------------------------------------------- head
__global__ __launch_bounds__(512)
void head_kernel(const float* __restrict__ hcat,
                 const float* __restrict__ W1, const float* __restrict__ b1,
                 const float* __restrict__ W2, const float* __restrict__ b2,
                 float* __restrict__ out)
{
    __shared__ float hc[4][192];
    __shared__ float h1[4][64];
    const int tid = threadIdx.x;
    for (int i = tid; i < 768; i += 512) hc[i / 192][i % 192] = hcat[i];
    __syncthreads();
    if (tid < 256) {
        int b = tid >> 6, e = tid & 63;
        float acc = b1[e];
        #pragma unroll
        for (int k = 0; k < 192; ++k) acc += hc[b][k] * W1[e * 192 + k];
        h1[b][e] = gelu_f(acc);
    }
    __syncthreads();
    for (int o = tid; o < 2000; o += 512) {
        int b = o / 500, n = o % 500;
        float acc = b2[n];
        #pragma unroll
        for (int k = 0; k < 64; ++k) acc += h1[b][k] * W2[n * 64 + k];
        out[o] = acc;
    }
}

// ================================================================ launch
extern "C" void kernel_launch(void* const* d_in, const int* in_sizes, int n_in,
                              void* d_out, int out_size, void* d_ws, size_t ws_size,
                              hipStream_t stream)
{
    (void)in_sizes; (void)n_in; (void)out_size; (void)ws_size;
    const float* x    = (const float*)d_in[0];
    const float* ipW  = (const float*)d_in[1];
    const float* ipb  = (const float*)d_in[2];
    const float* fe   = (const float*)d_in[3];
    const float* te   = (const float*)d_in[4];
    const float* glW  = (const float*)d_in[5];
    const float* glb  = (const float*)d_in[6];
    const float* glg  = (const float*)d_in[7];
    const float* glbe = (const float*)d_in[8];
    const float* Wih[3] = {(const float*)d_in[9],  (const float*)d_in[13], (const float*)d_in[17]};
    const float* Whh[3] = {(const float*)d_in[10], (const float*)d_in[14], (const float*)d_in[18]};
    const float* bih[3] = {(const float*)d_in[11], (const float*)d_in[15], (const float*)d_in[19]};
    const float* bhh[3] = {(const float*)d_in[12], (const float*)d_in[16], (const float*)d_in[20]};
    const float* W1 = (const float*)d_in[21];
    const float* b1 = (const float*)d_in[22];
    const float* W2 = (const float*)d_in[23];
    const float* b2 = (const float*)d_in[24];
    float* out = (float*)d_out;

    unsigned int* Xhl = (unsigned int*)d_ws;          // 32,768,000 uints (131 MB)
    unsigned int* Yhl = Xhl + 32768000;               // 32,768,000 uints (131 MB)
    short* adjTh = (short*)(Yhl + 32768000);          // 512*512 shorts
    short* adjTl = adjTh + NPAD * NPAD;
    short* glWh  = adjTl + NPAD * NPAD;               // 8192 shorts (2 layers)
    short* glWl  = glWh + 8192;
    short* ipWh  = glWl + 8192;                       // 2048 shorts
    short* ipWl  = ipWh + 2048;
    // GRU-phase scratch overlays Yhl (dead after layer-2):
    short* wbase = (short*)Yhl;
    short* Wh0 = wbase;                               // 6,144,000 shorts each
    short* Wl0 = Wh0 + 6144000;
    short* Wh1 = Wl0 + 6144000;
    short* Wl1 = Wh1 + 6144000;
    short* Wh2 = Wl1 + 6144000;
    short* Wl2 = Wh2 + 6144000;
    float* pbase = (float*)Yhl + 18432000;
    float* part0 = pbase;                             // 40*40*192   = 307,200
    float* part1 = part0 + 307200;                    // 40*80*192   = 614,400
    float* part2 = part1 + 614400;                    // 40*1024*192 = 7,864,320
    float* xp0   = part2 + 7864320;                   // 7,680
    float* xp1   = xp0 + 7680;                        // 15,360
    float* xp2   = xp1 + 15360;                       // 196,608
    float* hcat  = xp2 + 196608;                      // 768

    hipMemsetAsync(adjTh, 0, (size_t)NPAD * NPAD * 2 * sizeof(short), stream);
    adj_kernel<<<NN, 512, 0, stream>>>(fe, te, adjTh, adjTl);
    wsplit_kernel<<<8, 256, 0, stream>>>(glW, glWh, glWl, 2048);
    wsplit_kernel<<<2, 256, 0, stream>>>(ipW, ipWh, ipWl, 512);
    proj_mfma_kernel<<<4000, 256, 0, stream>>>(x, ipWh, ipWl, ipb, Xhl);

    // layer 1: Xhl -> Yhl (agg+residual), then h+LN in-place on Yhl
    agg_mfma_kernel<<<dim3(512, 4), 256, 0, stream>>>(Xhl, adjTh, adjTl, Yhl);
    hln_stream_kernel<<<4000, 256, 0, stream>>>(Yhl, glWh, glWl, glb, glg, glbe);
    // layer 2: Yhl -> Xhl, then in-place on Xhl
    agg_mfma_kernel<<<dim3(512, 4), 256, 0, stream>>>(Yhl, adjTh, adjTl, Xhl);
    hln_stream_kernel<<<4000, 256, 0, stream>>>(Xhl, glWh + 4096, glWl + 4096,
                                                glb + 64, glg + 64, glbe + 64);

    wconv_kernel<<<dim3(6000, 3), 256, 0, stream>>>(Wih[0], Wih[1], Wih[2],
                                                    Wh0, Wl0, Wh1, Wl1, Wh2, Wl2);
    gru_pre_mfma_kernel<<<760, 256, 0, stream>>>(Xhl, Wh0, Wl0, Wh1, Wl1, Wh2, Wl2,
                                                 part0, part1, part2);
    gru_reduce_fused_kernel<<<1144, 192, 0, stream>>>(part0, part1, part2,
                                                      bih[0], bih[1], bih[2],
                                                      xp0, xp1, xp2);
    gru_scan_kernel<<<12, 192, 0, stream>>>(xp0, xp1, xp2,
                                            Whh[0], Whh[1], Whh[2],
                                            bhh[0], bhh[1], bhh[2], hcat);
    head_kernel<<<1, 512, 0, stream>>>(hcat, W1, b1, W2, b2, out);
}

// Round 17
// 725.296 us; speedup vs baseline: 1.2273x; 1.0482x over previous
//
#include <hip/hip_runtime.h>
#include <math.h>

#define NN 500
#define DD 64
#define NPAD 512             // adjT padded to [512][512]
#define COLS 65536           // 1024 * 64
#define BS_TOT 1024          // B*S
#define I_DIM 32000          // N*D
#define KS_GRU 40            // K-split for GRU pre-GEMM
#define KSL 800              // 32000/40

typedef __attribute__((ext_vector_type(8))) short bf16x8;
typedef __attribute__((ext_vector_type(4))) float f32x4;

__device__ __forceinline__ float gelu_f(float x) {
    return 0.5f * x * (1.0f + erff(x * 0.70710678118654752440f));
}

__device__ __forceinline__ unsigned short bf16_rn(float x) {
    unsigned int u = __float_as_uint(x);
    unsigned int r = u + 0x7FFFu + ((u >> 16) & 1u);
    return (unsigned short)(r >> 16);
}
__device__ __forceinline__ float bf16_tof(unsigned short h) {
    return __uint_as_float(((unsigned int)h) << 16);
}
// packed split-bf16: u = hi | (lo<<16); value = tof(hi)+tof(lo)
__device__ __forceinline__ unsigned int pack_hl(float x) {
    unsigned short h = bf16_rn(x);
    unsigned short l = bf16_rn(x - bf16_tof(h));
    return (unsigned int)h | ((unsigned int)l << 16);
}
__device__ __forceinline__ float unpack_val(unsigned int u) {
    return __uint_as_float(u << 16) + __uint_as_float(u & 0xFFFF0000u);
}
__device__ __forceinline__ void split4(float4 v, short4& h4, short4& l4) {
    h4.x = (short)bf16_rn(v.x); l4.x = (short)bf16_rn(v.x - bf16_tof((unsigned short)h4.x));
    h4.y = (short)bf16_rn(v.y); l4.y = (short)bf16_rn(v.y - bf16_tof((unsigned short)h4.y));
    h4.z = (short)bf16_rn(v.z); l4.z = (short)bf16_rn(v.z - bf16_tof((unsigned short)h4.z));
    h4.w = (short)bf16_rn(v.w); l4.w = (short)bf16_rn(v.w - bf16_tof((unsigned short)h4.w));
}

// LDS XOR swizzle (16B granularity within 64B k-extent) — used by gru_pre
__device__ __forceinline__ int swz_k(int row, int kbyte) {
    return kbyte ^ (((row >> 3) & 3) << 4);
}

// fragment-major LDS byte offset: fragment (row>>4, q) holds 16 lanes x 16B
__device__ __forceinline__ int frag_off(int row, int q) {
    return ((((row >> 4) * 4 + q) * 16) + (row & 15)) * 16;
}

// ---------------------------------------------------------------- adjacency (+ identity fused)
// adjT[m][n] = softmax_m(from[n]·to[m]/0.5) + (m==n)  -> agg GEMM computes
// (adjT+I)·X = agg + residual in one pass, no epilogue re-read of X.
__global__ __launch_bounds__(512)
void adj_kernel(const float* __restrict__ fe, const float* __restrict__ te,
                short* __restrict__ adjTh, short* __restrict__ adjTl)
{
    __shared__ float fr[32];
    __shared__ float red[8];
    __shared__ float red2[8];
    const int n = blockIdx.x;
    const int tid = threadIdx.x;
    if (tid < 32) fr[tid] = fe[n * 32 + tid];
    __syncthreads();
    const int m = tid;
    float s = -1e30f;
    if (m < NN) {
        float acc = 0.f;
        #pragma unroll
        for (int f = 0; f < 32; ++f) acc += fr[f] * te[m * 32 + f];
        s = acc * 2.0f;   // 1/TEMP
    }
    float v = s;
    #pragma unroll
    for (int off = 32; off; off >>= 1) v = fmaxf(v, __shfl_xor(v, off));
    if ((tid & 63) == 0) red[tid >> 6] = v;
    __syncthreads();
    float bmax = red[0];
    #pragma unroll
    for (int i = 1; i < 8; ++i) bmax = fmaxf(bmax, red[i]);
    float e = (m < NN) ? expf(s - bmax) : 0.f;
    float v2 = e;
    #pragma unroll
    for (int off = 32; off; off >>= 1) v2 += __shfl_xor(v2, off);
    if ((tid & 63) == 0) red2[tid >> 6] = v2;
    __syncthreads();
    float bsum = 0.f;
    #pragma unroll
    for (int i = 0; i < 8; ++i) bsum += red2[i];
    if (m < NN) {
        float p = e / bsum + ((m == n) ? 1.0f : 0.0f);
        unsigned short h = bf16_rn(p);
        adjTh[(size_t)m * NPAD + n] = (short)h;
        adjTl[(size_t)m * NPAD + n] = (short)bf16_rn(p - bf16_tof(h));
    }
}

// ---------------------------------------------------------------- generic split-convert
__global__ __launch_bounds__(256)
void wsplit_kernel(const float* __restrict__ W, short* __restrict__ H,
                   short* __restrict__ L, int n4)
{
    int i = blockIdx.x * 256 + threadIdx.x;
    if (i < n4) {
        float4 v = *(const float4*)&W[i * 4];
        short4 h4, l4;
        split4(v, h4, l4);
        *(short4*)&H[i * 4] = h4;
        *(short4*)&L[i * 4] = l4;
    }
}

// ---------------------------------------------------------------- input proj (streaming MFMA, no LDS)
__global__ __launch_bounds__(256)
void proj_mfma_kernel(const float* __restrict__ xin,
                      const short* __restrict__ Wh, const short* __restrict__ Wl,
                      const float* __restrict__ ipb, unsigned int* __restrict__ Xhl)
{
    const int tid  = threadIdx.x;
    const int lane = tid & 63;
    const int wave = tid >> 6;
    const int q = lane >> 4, r16 = lane & 15;
    const size_t row0 = (size_t)blockIdx.x * 128 + wave * 32;

    float bB[4];
    #pragma unroll
    for (int ci = 0; ci < 4; ++ci) bB[ci] = ipb[ci * 16 + r16];

    bf16x8 wh[4], wl[4];
    #pragma unroll
    for (int ci = 0; ci < 4; ++ci) {
        int off = (ci * 16 + r16) * 32 + q * 8;
        wh[ci] = *(const bf16x8*)&Wh[off];
        wl[ci] = *(const bf16x8*)&Wl[off];
    }

    f32x4 acc[2][4];
    #pragma unroll
    for (int i = 0; i < 2; ++i)
        #pragma unroll
        for (int j = 0; j < 4; ++j) acc[i][j] = (f32x4){0.f, 0.f, 0.f, 0.f};

    #pragma unroll
    for (int mi = 0; mi < 2; ++mi) {
        const size_t row = row0 + mi * 16 + r16;
        const int n = (int)(row >> 10), bs = (int)(row & 1023);
        const float* src = &xin[((size_t)bs * NN + n) * 32 + q * 8];
        float4 v0 = *(const float4*)src;
        float4 v1 = *(const float4*)(src + 4);
        short4 h0, l0, h1, l1;
        split4(v0, h0, l0);
        split4(v1, h1, l1);
        bf16x8 ah, al;
        ah[0] = h0.x; ah[1] = h0.y; ah[2] = h0.z; ah[3] = h0.w;
        ah[4] = h1.x; ah[5] = h1.y; ah[6] = h1.z; ah[7] = h1.w;
        al[0] = l0.x; al[1] = l0.y; al[2] = l0.z; al[3] = l0.w;
        al[4] = l1.x; al[5] = l1.y; al[6] = l1.z; al[7] = l1.w;
        #pragma unroll
        for (int ci = 0; ci < 4; ++ci) {
            acc[mi][ci] = __builtin_amdgcn_mfma_f32_16x16x32_bf16(ah, wh[ci], acc[mi][ci], 0, 0, 0);
            acc[mi][ci] = __builtin_amdgcn_mfma_f32_16x16x32_bf16(ah, wl[ci], acc[mi][ci], 0, 0, 0);
            acc[mi][ci] = __builtin_amdgcn_mfma_f32_16x16x32_bf16(al, wh[ci], acc[mi][ci], 0, 0, 0);
        }
    }

    #pragma unroll
    for (int mi = 0; mi < 2; ++mi) {
        #pragma unroll
        for (int rg = 0; rg < 4; ++rg) {
            size_t grow = row0 + mi * 16 + q * 4 + rg;
            #pragma unroll
            for (int ci = 0; ci < 4; ++ci) {
                float y = gelu_f(acc[mi][ci][rg] + bB[ci]);
                Xhl[grow * 64 + ci * 16 + r16] = pack_hl(y);
            }
        }
    }
}

// ---------------------------------------------------------------- agg GEMM (split-bf16 MFMA, dbuf, fragment-major LDS)
// C[m][c] = sum_n (adjT+I)[m][n]*X[n][c]; packed in/out (residual fused in A).
__global__ __launch_bounds__(256)
void agg_mfma_kernel(const unsigned int* __restrict__ Xhl,
                     const short* __restrict__ adjTh, const short* __restrict__ adjTl,
                     unsigned int* __restrict__ Yhl)
{
    __shared__ __align__(16) short Ah[2][4096];
    __shared__ __align__(16) short Al[2][4096];
    __shared__ __align__(16) short Bh[2][4096];
    __shared__ __align__(16) short Bl[2][4096];

    const int tid  = threadIdx.x;
    const int lane = tid & 63;
    const int wave = tid >> 6;
    const int wm = (wave >> 1) * 64;
    const int wc = (wave & 1) * 64;
    const int q = lane >> 4, r16 = lane & 15;
    const int m0 = blockIdx.x * 128;   // m fastest: 4 siblings share B strip in L2
    const int c0 = blockIdx.y * 128;

    const int sa_m = tid >> 1, sa_kh = tid & 1;
    const int sb_c = tid & 127, sb_kh = tid >> 7;
    const size_t cb = (size_t)(c0 + sb_c);

    f32x4 acc[4][4];
    #pragma unroll
    for (int i = 0; i < 4; ++i)
        #pragma unroll
        for (int j = 0; j < 4; ++j) acc[i][j] = (f32x4){0.f, 0.f, 0.f, 0.f};

    // ---- prologue: stage chunk 0 into buffer 0
    {
        const size_t base = (size_t)(m0 + sa_m) * NPAD + sa_kh * 16;
        bf16x8 h0 = *(const bf16x8*)&adjTh[base];
        bf16x8 h1 = *(const bf16x8*)&adjTh[base + 8];
        bf16x8 l0 = *(const bf16x8*)&adjTl[base];
        bf16x8 l1 = *(const bf16x8*)&adjTl[base + 8];
        *(bf16x8*)((char*)Ah[0] + frag_off(sa_m, sa_kh * 2))     = h0;
        *(bf16x8*)((char*)Ah[0] + frag_off(sa_m, sa_kh * 2 + 1)) = h1;
        *(bf16x8*)((char*)Al[0] + frag_off(sa_m, sa_kh * 2))     = l0;
        *(bf16x8*)((char*)Al[0] + frag_off(sa_m, sa_kh * 2 + 1)) = l1;

        unsigned int u[16];
        #pragma unroll
        for (int j = 0; j < 16; ++j) {
            int kk = sb_kh * 16 + j;
            u[j] = (kk < NN) ? Xhl[(size_t)kk * COLS + cb] : 0u;
        }
        bf16x8 bh0, bh1, bl0, bl1;
        #pragma unroll
        for (int j = 0; j < 8; ++j) {
            bh0[j] = (short)(u[j] & 0xFFFFu);     bl0[j] = (short)(u[j] >> 16);
            bh1[j] = (short)(u[8 + j] & 0xFFFFu); bl1[j] = (short)(u[8 + j] >> 16);
        }
        *(bf16x8*)((char*)Bh[0] + frag_off(sb_c, sb_kh * 2))     = bh0;
        *(bf16x8*)((char*)Bh[0] + frag_off(sb_c, sb_kh * 2 + 1)) = bh1;
        *(bf16x8*)((char*)Bl[0] + frag_off(sb_c, sb_kh * 2))     = bl0;
        *(bf16x8*)((char*)Bl[0] + frag_off(sb_c, sb_kh * 2 + 1)) = bl1;
    }
    __syncthreads();

    for (int kc = 0; kc < 16; ++kc) {
        const int cur = kc & 1;
        // ---- (1) issue next-chunk global loads into registers
        bf16x8 nAh0, nAh1, nAl0, nAl1;
        unsigned int nu[16];
        if (kc < 15) {
            const int k0n = (kc + 1) * 32;
            const size_t base = (size_t)(m0 + sa_m) * NPAD + k0n + sa_kh * 16;
            nAh0 = *(const bf16x8*)&adjTh[base];
            nAh1 = *(const bf16x8*)&adjTh[base + 8];
            nAl0 = *(const bf16x8*)&adjTl[base];
            nAl1 = *(const bf16x8*)&adjTl[base + 8];
            #pragma unroll
            for (int j = 0; j < 16; ++j) {
                int kk = k0n + sb_kh * 16 + j;
                nu[j] = (kk < NN) ? Xhl[(size_t)kk * COLS + cb] : 0u;
            }
        }
        // ---- (2) compute current chunk from LDS buf cur (conflict-free frag reads)
        bf16x8 ah[4], al[4];
        #pragma unroll
        for (int mi = 0; mi < 4; ++mi) {
            int off = frag_off(wm + mi * 16 + r16, q);
            ah[mi] = *(const bf16x8*)((const char*)Ah[cur] + off);
            al[mi] = *(const bf16x8*)((const char*)Al[cur] + off);
        }
        #pragma unroll
        for (int ci = 0; ci < 4; ++ci) {
            int off = frag_off(wc + ci * 16 + r16, q);
            bf16x8 bh = *(const bf16x8*)((const char*)Bh[cur] + off);
            bf16x8 bl = *(const bf16x8*)((const char*)Bl[cur] + off);
            #pragma unroll
            for (int mi = 0; mi < 4; ++mi) {
                acc[mi][ci] = __builtin_amdgcn_mfma_f32_16x16x32_bf16(ah[mi], bh, acc[mi][ci], 0, 0, 0);
                acc[mi][ci] = __builtin_amdgcn_mfma_f32_16x16x32_bf16(ah[mi], bl, acc[mi][ci], 0, 0, 0);
                acc[mi][ci] = __builtin_amdgcn_mfma_f32_16x16x32_bf16(al[mi], bh, acc[mi][ci], 0, 0, 0);
            }
        }
        // ---- (3) write next chunk into buf cur^1
        if (kc < 15) {
            const int nb = cur ^ 1;
            *(bf16x8*)((char*)Ah[nb] + frag_off(sa_m, sa_kh * 2))     = nAh0;
            *(bf16x8*)((char*)Ah[nb] + frag_off(sa_m, sa_kh * 2 + 1)) = nAh1;
            *(bf16x8*)((char*)Al[nb] + frag_off(sa_m, sa_kh * 2))     = nAl0;
            *(bf16x8*)((char*)Al[nb] + frag_off(sa_m, sa_kh * 2 + 1)) = nAl1;
            bf16x8 bh0, bh1, bl0, bl1;
            #pragma unroll
            for (int j = 0; j < 8; ++j) {
                bh0[j] = (short)(nu[j] & 0xFFFFu);     bl0[j] = (short)(nu[j] >> 16);
                bh1[j] = (short)(nu[8 + j] & 0xFFFFu); bl1[j] = (short)(nu[8 + j] >> 16);
            }
            *(bf16x8*)((char*)Bh[nb] + frag_off(sb_c, sb_kh * 2))     = bh0;
            *(bf16x8*)((char*)Bh[nb] + frag_off(sb_c, sb_kh * 2 + 1)) = bh1;
            *(bf16x8*)((char*)Bl[nb] + frag_off(sb_c, sb_kh * 2))     = bl0;
            *(bf16x8*)((char*)Bl[nb] + frag_off(sb_c, sb_kh * 2 + 1)) = bl1;
        }
        // ---- (4) single barrier per chunk
        __syncthreads();
    }

    // ---- epilogue: store packed (residual already in A via identity)
    #pragma unroll
    for (int mi = 0; mi < 4; ++mi) {
        #pragma unroll
        for (int r = 0; r < 4; ++r) {
            int m = m0 + wm + mi * 16 + q * 4 + r;
            if (m < NN) {
                #pragma unroll
                for (int ci = 0; ci < 4; ++ci) {
                    size_t idx = (size_t)m * COLS + c0 + wc + ci * 16 + r16;
                    Yhl[idx] = pack_hl(acc[mi][ci][r]);
                }
            }
        }
    }
}

// ---------------------------------------------------------------- h + LN, streaming MFMA (no LDS, no barriers, in-place)
__global__ __launch_bounds__(256)
void hln_stream_kernel(unsigned int* __restrict__ Xio,
                       const short* __restrict__ Wh, const short* __restrict__ Wl,
                       const float* __restrict__ glb, const float* __restrict__ glg,
                       const float* __restrict__ glbe)
{
    const int tid  = threadIdx.x;
    const int lane = tid & 63;
    const int wave = tid >> 6;
    const int q = lane >> 4, r16 = lane & 15;
    const size_t row0 = (size_t)blockIdx.x * 128 + wave * 32;

    float bB2[4], bG2[4], bE2[4];
    #pragma unroll
    for (int ci = 0; ci < 4; ++ci) {
        int e = ci * 16 + r16;
        bB2[ci] = glb[e]; bG2[ci] = glg[e]; bE2[ci] = glbe[e];
    }

    f32x4 acc[2][4];
    #pragma unroll
    for (int i = 0; i < 2; ++i)
        #pragma unroll
        for (int j = 0; j < 4; ++j) acc[i][j] = (f32x4){0.f, 0.f, 0.f, 0.f};

    #pragma unroll
    for (int kh = 0; kh < 2; ++kh) {
        bf16x8 wh[4], wl[4];
        #pragma unroll
        for (int ci = 0; ci < 4; ++ci) {
            int off = (ci * 16 + r16) * 64 + kh * 32 + q * 8;
            wh[ci] = *(const bf16x8*)&Wh[off];
            wl[ci] = *(const bf16x8*)&Wl[off];
        }
        #pragma unroll
        for (int mi = 0; mi < 2; ++mi) {
            const size_t row = row0 + mi * 16 + r16;
            const unsigned int* src = &Xio[row * 64 + kh * 32 + q * 8];
            uint4 u0 = *(const uint4*)src;
            uint4 u1 = *(const uint4*)(src + 4);
            bf16x8 ah, al;
            ah[0] = (short)(u0.x & 0xFFFFu); al[0] = (short)(u0.x >> 16);
            ah[1] = (short)(u0.y & 0xFFFFu); al[1] = (short)(u0.y >> 16);
            ah[2] = (short)(u0.z & 0xFFFFu); al[2] = (short)(u0.z >> 16);
            ah[3] = (short)(u0.w & 0xFFFFu); al[3] = (short)(u0.w >> 16);
            ah[4] = (short)(u1.x & 0xFFFFu); al[4] = (short)(u1.x >> 16);
            ah[5] = (short)(u1.y & 0xFFFFu); al[5] = (short)(u1.y >> 16);
            ah[6] = (short)(u1.z & 0xFFFFu); al[6] = (short)(u1.z >> 16);
            ah[7] = (short)(u1.w & 0xFFFFu); al[7] = (short)(u1.w >> 16);
            #pragma unroll
            for (int ci = 0; ci < 4; ++ci) {
                acc[mi][ci] = __builtin_amdgcn_mfma_f32_16x16x32_bf16(ah, wh[ci], acc[mi][ci], 0, 0, 0);
                acc[mi][ci] = __builtin_amdgcn_mfma_f32_16x16x32_bf16(ah, wl[ci], acc[mi][ci], 0, 0, 0);
                acc[mi][ci] = __builtin_amdgcn_mfma_f32_16x16x32_bf16(al, wh[ci], acc[mi][ci], 0, 0, 0);
            }
        }
    }

    #pragma unroll
    for (int mi = 0; mi < 2; ++mi) {
        #pragma unroll
        for (int rg = 0; rg < 4; ++rg) {
            float h[4];
            float s1 = 0.f;
            #pragma unroll
            for (int ci = 0; ci < 4; ++ci) {
                h[ci] = gelu_f(acc[mi][ci][rg] + bB2[ci]);
                s1 += h[ci];
            }
            #pragma unroll
            for (int off = 1; off < 16; off <<= 1) s1 += __shfl_xor(s1, off);
            float mu = s1 * (1.f / 64.f);
            float s2 = 0.f;
            #pragma unroll
            for (int ci = 0; ci < 4; ++ci) { float dc = h[ci] - mu; s2 += dc * dc; }
            #pragma unroll
            for (int off = 1; off < 16; off <<= 1) s2 += __shfl_xor(s2, off);
            float rs = 1.f / sqrtf(s2 * (1.f / 64.f) + 1e-5f);
            size_t grow = row0 + mi * 16 + q * 4 + rg;
            #pragma unroll
            for (int ci = 0; ci < 4; ++ci) {
                float y = (h[ci] - mu) * rs * bG2[ci] + bE2[ci];
                Xio[grow * 64 + ci * 16 + r16] = pack_hl(y);
            }
        }
    }
}

// ---------------------------------------------------------------- Wih split-convert
__global__ __launch_bounds__(256)
void wconv_kernel(const float* __restrict__ W0, const float* __restrict__ W1,
                  const float* __restrict__ W2,
                  short* __restrict__ h0, short* __restrict__ l0,
                  short* __restrict__ h1, short* __restrict__ l1,
                  short* __restrict__ h2, short* __restrict__ l2)
{
    const int gi = blockIdx.y;
    const float* W = (gi == 0) ? W0 : (gi == 1) ? W1 : W2;
    short* H = (gi == 0) ? h0 : (gi == 1) ? h1 : h2;
    short* L = (gi == 0) ? l0 : (gi == 1) ? l1 : l2;
    const size_t i = ((size_t)blockIdx.x * 256 + threadIdx.x) * 4;
    float4 v = *(const float4*)&W[i];
    short4 h4, l4;
    split4(v, h4, l4);
    *(short4*)&H[i] = h4;
    *(short4*)&L[i] = l4;
}

// ---------------------------------------------------------------- GRU pre-GEMM (MFMA)
__global__ __launch_bounds__(256)
void gru_pre_mfma_kernel(const unsigned int* __restrict__ Xhl,
                         const short* __restrict__ Wh0, const short* __restrict__ Wl0,
                         const short* __restrict__ Wh1, const short* __restrict__ Wl1,
                         const short* __restrict__ Wh2, const short* __restrict__ Wl2,
                         float* __restrict__ p0, float* __restrict__ p1,
                         float* __restrict__ p2)
{
    __shared__ __align__(16) short Ah[64 * 40];
    __shared__ __align__(16) short Al[64 * 40];
    __shared__ __align__(16) short Bh[192 * 40];
    __shared__ __align__(16) short Bl[192 * 40];

    const int bid = blockIdx.x;
    int gi, mtid, ks;
    if (bid < 40)       { gi = 0; mtid = 0;             ks = bid; }
    else if (bid < 120) { int r = bid - 40;  gi = 1; ks = r % 40; mtid = r / 40; }
    else                { int r = bid - 120; gi = 2; ks = r % 40; mtid = r / 40; }
    const short* Wh = (gi == 0) ? Wh0 : (gi == 1) ? Wh1 : Wh2;
    const short* Wl = (gi == 0) ? Wl0 : (gi == 1) ? Wl1 : Wl2;
    float* partial  = (gi == 0) ? p0 : (gi == 1) ? p1 : p2;
    const int Trows = (gi == 0) ? 10 : (gi == 1) ? 20 : 256;
    const int toff  = (gi == 0) ? 246 : (gi == 1) ? 236 : 0;
    const int M     = (gi == 0) ? 40 : (gi == 1) ? 80 : 1024;
    const int R0 = mtid * 64;

    const int tid  = threadIdx.x;
    const int lane = tid & 63;
    const int wave = tid >> 6;
    const int wr = (wave & 1) * 32;
    const int wg = (wave >> 1) * 96;
    const int q = lane >> 4, r16 = lane & 15;

    const int sa_r = tid >> 2, sa_kq = tid & 3;
    const bool vldA = (R0 + sa_r < M);
    int btA = 0;
    if (vldA) { int R = R0 + sa_r; int b = R / Trows, t = R - b * Trows; btA = b * 256 + toff + t; }

    f32x4 acc[2][6];
    #pragma unroll
    for (int i = 0; i < 2; ++i)
        #pragma unroll
        for (int j = 0; j < 6; ++j) acc[i][j] = (f32x4){0.f, 0.f, 0.f, 0.f};

    for (int c = 0; c < KSL / 32; ++c) {
        const int k0 = ks * KSL + c * 32;
        {
            const int kk = k0 + sa_kq * 8;
            const int nn = kk >> 6, d0 = kk & 63;
            uint4 u0 = make_uint4(0u, 0u, 0u, 0u), u1 = u0;
            if (vldA) {
                const unsigned int* src = &Xhl[((size_t)nn * BS_TOT + btA) * 64 + d0];
                u0 = *(const uint4*)src;
                u1 = *(const uint4*)(src + 4);
            }
            short4 h0 = make_short4((short)(u0.x & 0xFFFF), (short)(u0.y & 0xFFFF),
                                    (short)(u0.z & 0xFFFF), (short)(u0.w & 0xFFFF));
            short4 l0 = make_short4((short)(u0.x >> 16), (short)(u0.y >> 16),
                                    (short)(u0.z >> 16), (short)(u0.w >> 16));
            short4 h1 = make_short4((short)(u1.x & 0xFFFF), (short)(u1.y & 0xFFFF),
                                    (short)(u1.z & 0xFFFF), (short)(u1.w & 0xFFFF));
            short4 l1 = make_short4((short)(u1.x >> 16), (short)(u1.y >> 16),
                                    (short)(u1.z >> 16), (short)(u1.w >> 16));
            int kb = swz_k(sa_r, sa_kq * 16);
            char* rowH = (char*)Ah + sa_r * 80;
            char* rowL = (char*)Al + sa_r * 80;
            *(short4*)(rowH + kb) = h0; *(short4*)(rowH + kb + 8) = h1;
            *(short4*)(rowL + kb) = l0; *(short4*)(rowL + kb + 8) = l1;
        }
        #pragma unroll
        for (int l = 0; l < 3; ++l) {
            int idx = tid + l * 256;
            int g = idx >> 2, kq = idx & 3;
            const size_t src = (size_t)g * I_DIM + k0 + kq * 8;
            bf16x8 hv = *(const bf16x8*)&Wh[src];
            bf16x8 lv = *(const bf16x8*)&Wl[src];
            int kb = swz_k(g, kq * 16);
            *(bf16x8*)((char*)Bh + g * 80 + kb) = hv;
            *(bf16x8*)((char*)Bl + g * 80 + kb) = lv;
        }
        __syncthreads();
        bf16x8 ah[2], al[2];
        #pragma unroll
        for (int mi = 0; mi < 2; ++mi) {
            int row = wr + mi * 16 + r16;
            int kb = swz_k(row, q * 16);
            ah[mi] = *(const bf16x8*)((const char*)Ah + row * 80 + kb);
            al[mi] = *(const bf16x8*)((const char*)Al + row * 80 + kb);
        }
        #pragma unroll
        for (int ci = 0; ci < 6; ++ci) {
            int grow = wg + ci * 16 + r16;
            int kb = swz_k(grow, q * 16);
            bf16x8 bh = *(const bf16x8*)((const char*)Bh + grow * 80 + kb);
            bf16x8 bl = *(const bf16x8*)((const char*)Bl + grow * 80 + kb);
            #pragma unroll
            for (int mi = 0; mi < 2; ++mi) {
                acc[mi][ci] = __builtin_amdgcn_mfma_f32_16x16x32_bf16(ah[mi], bh, acc[mi][ci], 0, 0, 0);
                acc[mi][ci] = __builtin_amdgcn_mfma_f32_16x16x32_bf16(ah[mi], bl, acc[mi][ci], 0, 0, 0);
                acc[mi][ci] = __builtin_amdgcn_mfma_f32_16x16x32_bf16(al[mi], bh, acc[mi][ci], 0, 0, 0);
            }
        }
        __syncthreads();
    }
    #pragma unroll
    for (int mi = 0; mi < 2; ++mi) {
        #pragma unroll
        for (int r = 0; r < 4; ++r) {
            int R = R0 + wr + mi * 16 + q * 4 + r;
            if (R < M) {
                #pragma unroll
                for (int ci = 0; ci < 6; ++ci)
                    partial[((size_t)ks * M + R) * 192 + wg + ci * 16 + r16] = acc[mi][ci][r];
            }
        }
    }
}

// ---------------------------------------------------------------- reduce (all 3 fused)
__global__ __launch_bounds__(192)
void gru_reduce_fused_kernel(const float* __restrict__ p0, const float* __restrict__ p1,
                             const float* __restrict__ p2,
                             const float* __restrict__ bih0, const float* __restrict__ bih1,
                             const float* __restrict__ bih2,
                             float* __restrict__ xp0, float* __restrict__ xp1,
                             float* __restrict__ xp2)
{
    int r = blockIdx.x;
    const float* partial; const float* bih; float* xp; int M;
    if (r < 40)       { partial = p0; bih = bih0; xp = xp0; M = 40; }
    else if (r < 120) { r -= 40;  partial = p1; bih = bih1; xp = xp1; M = 80; }
    else              { r -= 120; partial = p2; bih = bih2; xp = xp2; M = 1024; }
    const int g = threadIdx.x;
    float acc = bih[g];
    for (int ks = 0; ks < KS_GRU; ++ks)
        acc += partial[((size_t)ks * M + r) * 192 + g];
    xp[(size_t)r * 192 + g] = acc;
}

// ---------------------------------------------------------------- GRU scan
__global__ __launch_bounds__(192)
void gru_scan_kernel(const float* __restrict__ xp_s, const float* __restrict__ xp_m,
                     const float* __restrict__ xp_l,
                     const float* __restrict__ Whh_s, const float* __restrict__ Whh_m,
                     const float* __restrict__ Whh_l,
                     const float* __restrict__ bhh_s, const float* __restrict__ bhh_m,
                     const float* __restrict__ bhh_l,
                     float* __restrict__ hcat)
{
    __shared__ float h[64];
    __shared__ float gh[192];
    const int blk = blockIdx.x;
    const int g3 = blk >> 2, b = blk & 3;
    const float* xp  = (g3 == 0) ? xp_s : (g3 == 1) ? xp_m : xp_l;
    const float* Whh = (g3 == 0) ? Whh_s : (g3 == 1) ? Whh_m : Whh_l;
    const float* bhh = (g3 == 0) ? bhh_s : (g3 == 1) ? bhh_m : bhh_l;
    const int T = (g3 == 0) ? 10 : (g3 == 1) ? 20 : 256;
    const int g = threadIdx.x;

    float w[64];
    #pragma unroll
    for (int k4 = 0; k4 < 16; ++k4) {
        float4 v = *(const float4*)&Whh[g * 64 + k4 * 4];
        w[k4 * 4 + 0] = v.x; w[k4 * 4 + 1] = v.y;
        w[k4 * 4 + 2] = v.z; w[k4 * 4 + 3] = v.w;
    }
    const float bh = bhh[g];
    if (g < 64) h[g] = 0.f;

    const float* xpb = xp + (size_t)b * T * 192;
    float xr_c = 0.f, xz_c = 0.f, xn_c = 0.f;
    if (g < 64) { xr_c = xpb[g]; xz_c = xpb[64 + g]; xn_c = xpb[128 + g]; }
    __syncthreads();

    for (int t = 0; t < T; ++t) {
        float xr_n = 0.f, xz_n = 0.f, xn_n = 0.f;
        if (t + 1 < T && g < 64) {
            const float* xq = xpb + (size_t)(t + 1) * 192;
            xr_n = xq[g]; xz_n = xq[64 + g]; xn_n = xq[128 + g];
        }
        float a0 = 0.f, a1 = 0.f, a2 = 0.f, a3 = 0.f;
        #pragma unroll
        for (int k4 = 0; k4 < 16; ++k4) {
            float4 hv = ((const float4*)h)[k4];
            a0 += hv.x * w[k4 * 4 + 0];
            a1 += hv.y * w[k4 * 4 + 1];
            a2 += hv.z * w[k4 * 4 + 2];
            a3 += hv.w * w[k4 * 4 + 3];
        }
        gh[g] = bh + ((a0 + a1) + (a2 + a3));
        __syncthreads();
        if (g < 64) {
            float hr = gh[g], hz = gh[64 + g], hn = gh[128 + g];
            float r = 1.f / (1.f + __expf(-(xr_c + hr)));
            float z = 1.f / (1.f + __expf(-(xz_c + hz)));
            float pre = xn_c + r * hn;
            float e2 = __expf(2.f * pre);
            float nv = 1.f - 2.f / (e2 + 1.f);   // tanh
            h[g] = (1.f - z) * nv + z * h[g];
        }
        __syncthreads();
        xr_c = xr_n; xz_c = xz_n; xn_c = xn_n;
    }
    if (g < 64) hcat[b * 192 + g3 * 64 + g] = h[g];
}

// ---------------------------------------------------------------- head
__global__ __launch_bounds__(512)
void head_kernel(const float* __restrict__ hcat,
                 const float* __restrict__ W1, const float* __restrict__ b1,
                 const float* __restrict__ W2, const float* __restrict__ b2,
                 float* __restrict__ out)
{
    __shared__ float hc[4][192];
    __shared__ float h1[4][64];
    const int tid = threadIdx.x;
    for (int i = tid; i < 768; i += 512) hc[i / 192][i % 192] = hcat[i];
    __syncthreads();
    if (tid < 256) {
        int b = tid >> 6, e = tid & 63;
        float acc = b1[e];
        #pragma unroll
        for (int k = 0; k < 192; ++k) acc += hc[b][k] * W1[e * 192 + k];
        h1[b][e] = gelu_f(acc);
    }
    __syncthreads();
    for (int o = tid; o < 2000; o += 512) {
        int b = o / 500, n = o % 500;
        float acc = b2[n];
        #pragma unroll
        for (int k = 0; k < 64; ++k) acc += h1[b][k] * W2[n * 64 + k];
        out[o] = acc;
    }
}

// ================================================================ launch
extern "C" void kernel_launch(void* const* d_in, const int* in_sizes, int n_in,
                              void* d_out, int out_size, void* d_ws, size_t ws_size,
                              hipStream_t stream)
{
    (void)in_sizes; (void)n_in; (void)out_size; (void)ws_size;
    const float* x    = (const float*)d_in[0];
    const float* ipW  = (const float*)d_in[1];
    const float* ipb  = (const float*)d_in[2];
    const float* fe   = (const float*)d_in[3];
    const float* te   = (const float*)d_in[4];
    const float* glW  = (const float*)d_in[5];
    const float* glb  = (const float*)d_in[6];
    const float* glg  = (const float*)d_in[7];
    const float* glbe = (const float*)d_in[8];
    const float* Wih[3] = {(const float*)d_in[9],  (const float*)d_in[13], (const float*)d_in[17]};
    const float* Whh[3] = {(const float*)d_in[10], (const float*)d_in[14], (const float*)d_in[18]};
    const float* bih[3] = {(const float*)d_in[11], (const float*)d_in[15], (const float*)d_in[19]};
    const float* bhh[3] = {(const float*)d_in[12], (const float*)d_in[16], (const float*)d_in[20]};
    const float* W1 = (const float*)d_in[21];
    const float* b1 = (const float*)d_in[22];
    const float* W2 = (const float*)d_in[23];
    const float* b2 = (const float*)d_in[24];
    float* out = (float*)d_out;

    unsigned int* Xhl = (unsigned int*)d_ws;          // 32,768,000 uints (131 MB)
    unsigned int* Yhl = Xhl + 32768000;               // 32,768,000 uints (131 MB)
    short* adjTh = (short*)(Yhl + 32768000);          // 512*512 shorts
    short* adjTl = adjTh + NPAD * NPAD;
    short* glWh  = adjTl + NPAD * NPAD;               // 8192 shorts (2 layers)
    short* glWl  = glWh + 8192;
    short* ipWh  = glWl + 8192;                       // 2048 shorts
    short* ipWl  = ipWh + 2048;
    // GRU-phase scratch overlays Yhl (dead after layer-2):
    short* wbase = (short*)Yhl;
    short* Wh0 = wbase;                               // 6,144,000 shorts each
    short* Wl0 = Wh0 + 6144000;
    short* Wh1 = Wl0 + 6144000;
    short* Wl1 = Wh1 + 6144000;
    short* Wh2 = Wl1 + 6144000;
    short* Wl2 = Wh2 + 6144000;
    float* pbase = (float*)Yhl + 18432000;
    float* part0 = pbase;                             // 40*40*192   = 307,200
    float* part1 = part0 + 307200;                    // 40*80*192   = 614,400
    float* part2 = part1 + 614400;                    // 40*1024*192 = 7,864,320
    float* xp0   = part2 + 7864320;                   // 7,680
    float* xp1   = xp0 + 7680;                        // 15,360
    float* xp2   = xp1 + 15360;                       // 196,608
    float* hcat  = xp2 + 196608;                      // 768

    hipMemsetAsync(adjTh, 0, (size_t)NPAD * NPAD * 2 * sizeof(short), stream);
    adj_kernel<<<NN, 512, 0, stream>>>(fe, te, adjTh, adjTl);
    wsplit_kernel<<<8, 256, 0, stream>>>(glW, glWh, glWl, 2048);
    wsplit_kernel<<<2, 256, 0, stream>>>(ipW, ipWh, ipWl, 512);
    proj_mfma_kernel<<<4000, 256, 0, stream>>>(x, ipWh, ipWl, ipb, Xhl);

    // layer 1: Xhl -> Yhl ((adjT+I)·X), then h+LN in-place on Yhl
    agg_mfma_kernel<<<dim3(4, 512), 256, 0, stream>>>(Xhl, adjTh, adjTl, Yhl);
    hln_stream_kernel<<<4000, 256, 0, stream>>>(Yhl, glWh, glWl, glb, glg, glbe);
    // layer 2: Yhl -> Xhl, then in-place on Xhl
    agg_mfma_kernel<<<dim3(4, 512), 256, 0, stream>>>(Yhl, adjTh, adjTl, Xhl);
    hln_stream_kernel<<<4000, 256, 0, stream>>>(Xhl, glWh + 4096, glWl + 4096,
                                                glb + 64, glg + 64, glbe + 64);

    wconv_kernel<<<dim3(6000, 3), 256, 0, stream>>>(Wih[0], Wih[1], Wih[2],
                                                    Wh0, Wl0, Wh1, Wl1, Wh2, Wl2);
    gru_pre_mfma_kernel<<<760, 256, 0, stream>>>(Xhl, Wh0, Wl0, Wh1, Wl1, Wh2, Wl2,
                                                 part0, part1, part2);
    gru_reduce_fused_kernel<<<1144, 192, 0, stream>>>(part0, part1, part2,
                                                      bih[0], bih[1], bih[2],
                                                      xp0, xp1, xp2);
    gru_scan_kernel<<<12, 192, 0, stream>>>(xp0, xp1, xp2,
                                            Whh[0], Whh[1], Whh[2],
                                            bhh[0], bhh[1], bhh[2], hcat);
    head_kernel<<<1, 512, 0, stream>>>(hcat, W1, b1, W2, b2, out);
}